// Round 6
// baseline (512.449 us; speedup 1.0000x reference)
//
#include <hip/hip_runtime.h>
#include <hip/hip_bf16.h>
#include <math.h>

// ---------------------------------------------------------------------------
// FusionBlock_DenseAVInteractions — round 10
//
// Round-9 (184.2 us, prediction matched): vectorized 64x64 transposes.
// Accounting: ~76 us harness fills + ~44 us estimated kernel work + ~60 us
// unexplained -> suspect per-dispatch serialization gaps (8 dependent
// launches). Round-1's persistent failure was an OCCUPANCY failure (LDS
// union + grid residency capped all phases at 2 blk/CU), not barrier cost.
//
// Round-10: fuse ONLY the tail (attn, ygemm, ln, mlp1, mlp2, reduce) into
// one cooperative kernel: 512 blocks x 256 thr, launch_bounds(256,2),
// LDS union 24 KB -> 2 blk/CU co-residency guaranteed; every phase keeps
// its exact standalone occupancy. 5 launch boundaries -> 5 gsync barriers
// (round-1-verified pattern). Phase bodies byte-identical to round-9.
// prep/projT (high-occupancy launches) stay separate. 8 launches -> 3.
// ---------------------------------------------------------------------------

typedef unsigned short ushort_t;
typedef __attribute__((ext_vector_type(8))) __bf16 bf16x8;
typedef __attribute__((ext_vector_type(4))) float f32x4;

#define DEVFN static __device__ __forceinline__

DEVFN ushort_t f2bf(float f) {
    unsigned int x = __float_as_uint(f);
    unsigned int r = x + 0x7FFFu + ((x >> 16) & 1u);  // RNE
    return (ushort_t)(r >> 16);
}
// unpack 8 bf16 (uint4) -> 8 floats
DEVFN void unpack8(uint4 dv, float* dst) {
    unsigned int ws[4] = {dv.x, dv.y, dv.z, dv.w};
#pragma unroll
    for (int i = 0; i < 4; i++) {
        dst[2 * i] = __uint_as_float(ws[i] << 16);
        dst[2 * i + 1] = __uint_as_float(ws[i] & 0xFFFF0000u);
    }
}

// ---------------------------------------------------------------------------
// Device-wide barrier (round-1-verified). All gridDim.x blocks co-resident.
// ---------------------------------------------------------------------------
DEVFN void gsync(unsigned int* c) {
    __syncthreads();
    if (threadIdx.x == 0) {
        __threadfence();
        __hip_atomic_fetch_add(c, 1u, __ATOMIC_RELEASE, __HIP_MEMORY_SCOPE_AGENT);
        unsigned int nb = gridDim.x;
        unsigned int tries = 0;
        while (__hip_atomic_load(c, __ATOMIC_ACQUIRE, __HIP_MEMORY_SCOPE_AGENT) < nb) {
            __builtin_amdgcn_s_sleep(1);
            if (++tries > (1u << 22)) break;  // escape hatch: fail, not hang
        }
        __threadfence();
    }
    __syncthreads();
}

// ---------------------------------------------------------------------------
// LayerNorm body: 256 threads per row of 1024. fp32 in -> bf16 out.
// ---------------------------------------------------------------------------
DEVFN void ln_body(const float* __restrict__ x, const float* __restrict__ w,
                   const float* __restrict__ b, ushort_t* __restrict__ out,
                   int row) {
    const float4* xr4 = (const float4*)(x + (size_t)row * 1024);
    ushort_t* orow = out + (size_t)row * 1024;
    int tid = threadIdx.x;
    float4 v4 = xr4[tid];
    float s = v4.x + v4.y + v4.z + v4.w;
    float ss = v4.x * v4.x + v4.y * v4.y + v4.z * v4.z + v4.w * v4.w;
#pragma unroll
    for (int off = 32; off > 0; off >>= 1) {
        s += __shfl_down(s, off);
        ss += __shfl_down(ss, off);
    }
    __shared__ float red[8];
    if ((tid & 63) == 0) {
        red[tid >> 6] = s;
        red[4 + (tid >> 6)] = ss;
    }
    __syncthreads();
    s = red[0] + red[1] + red[2] + red[3];
    ss = red[4] + red[5] + red[6] + red[7];
    float mean = s * (1.f / 1024.f);
    float var = ss * (1.f / 1024.f) - mean * mean;
    float rstd = rsqrtf(var + 1e-5f);
    const float4 w4 = ((const float4*)w)[tid];
    const float4 b4 = ((const float4*)b)[tid];
    union { ushort_t u[4]; uint2 v; } pk;
    pk.u[0] = f2bf((v4.x - mean) * rstd * w4.x + b4.x);
    pk.u[1] = f2bf((v4.y - mean) * rstd * w4.y + b4.y);
    pk.u[2] = f2bf((v4.z - mean) * rstd * w4.z + b4.z);
    pk.u[3] = f2bf((v4.w - mean) * rstd * w4.w + b4.w);
    *(uint2*)(&orow[tid * 4]) = pk.v;
}

struct LNSeg {
    const float* x; const float* w; const float* b; ushort_t* out; int start;
};
struct TDesc { const float* in; ushort_t* out; int R, C, nx, start; };

// ---------------------------------------------------------------------------
// 64x64 transpose tile (fp32 [R,C] -> bf16 [C,R]), vectorized (round-9).
// ---------------------------------------------------------------------------
DEVFN void transpose_body(TDesc d, int t, ushort_t* lds) {
    int bx = (t % d.nx) * 64;
    int by = (t / d.nx) * 64;
    int tid = threadIdx.x;
#pragma unroll
    for (int it = 0; it < 4; it++) {
        int idx = it * 256 + tid;        // 0..1023
        int r = idx >> 4;                // 0..63
        int c4 = (idx & 15) << 2;        // 0,4,...,60
        float4 v = *(const float4*)(&d.in[(size_t)(by + r) * d.C + bx + c4]);
        float vals[4] = {v.x, v.y, v.z, v.w};
#pragma unroll
        for (int j = 0; j < 4; j++) {
            int c = c4 + j;
            int rs = (r + (((c >> 2) & 7) << 3)) & 63;
            lds[c * 64 + rs] = f2bf(vals[j]);
        }
    }
    __syncthreads();
#pragma unroll
    for (int it = 0; it < 2; it++) {
        int idx = it * 256 + tid;        // 0..511
        int c = idx >> 3;                // 0..63
        int l8 = idx & 7;
        int rs = ((l8 << 3) + (((c >> 2) & 7) << 3)) & 63;
        uint4 val = *(const uint4*)(&lds[c * 64 + rs]);
        *(uint4*)(&d.out[(size_t)(bx + c) * d.R + by + (l8 << 3)]) = val;
    }
    __syncthreads();  // safe LDS reuse by caller
}

// ---------------------------------------------------------------------------
// prep: blocks [0,896) = 3 LayerNorms; rest = Wq/Wkv transposes.
// ---------------------------------------------------------------------------
__global__ __launch_bounds__(256) void prep_kernel(LNSeg l0, LNSeg l1,
                                                   LNSeg l2, TDesc d0,
                                                   TDesc d1) {
    int id = blockIdx.x;
    if (id < 896) {
        LNSeg s = (id >= l2.start) ? l2 : ((id >= l1.start) ? l1 : l0);
        ln_body(s.x, s.w, s.b, s.out, id - s.start);
        return;
    }
    id -= 896;
    __shared__ ushort_t tile[64 * 64];
    TDesc d = (id >= d1.start) ? d1 : d0;
    transpose_body(d, id - d.start, tile);
}

// ---------------------------------------------------------------------------
// Pipelined MFMA bf16 GEMM core, BK=64: 64x64 tile, 256 threads (2x2 waves),
// LS=72. EPI: 0 = bf16 store; 2 = +bias +exact GELU, bf16;
// 3 = +bias +resid, fp32; 4 = raw fp32 store (split-K partial)
// ---------------------------------------------------------------------------
template <int EPI, typename OutT>
DEVFN void gemm64_core(const ushort_t* __restrict__ A, int lda,
                       const ushort_t* __restrict__ B, int ldb,
                       OutT* __restrict__ C, int ldc,
                       const float* __restrict__ bias,
                       const float* __restrict__ resid, int K, int m0, int n0,
                       ushort_t* As, ushort_t* Bs) {
    constexpr int LS = 72;
    int tid = threadIdx.x;
    int wave = tid >> 6, lane = tid & 63;
    int wm = wave >> 1, wn = wave & 1;
    int quad = lane >> 4, l16 = lane & 15;

    f32x4 acc[2][2];
#pragma unroll
    for (int i = 0; i < 2; i++)
#pragma unroll
        for (int j = 0; j < 2; j++) acc[i][j] = (f32x4){0.f, 0.f, 0.f, 0.f};

    int r = tid >> 3;  // 0..31
    int c = tid & 7;   // k-chunk of 8 bf16
    const ushort_t* Ap = A + (size_t)(m0 + r) * lda + c * 8;
    const ushort_t* Bp = B + (size_t)(n0 + r) * ldb + c * 8;
    const ushort_t* Ap2 = Ap + (size_t)32 * lda;
    const ushort_t* Bp2 = Bp + (size_t)32 * ldb;
    uint4 ra = *(const uint4*)Ap, ra2 = *(const uint4*)Ap2;
    uint4 rb = *(const uint4*)Bp, rb2 = *(const uint4*)Bp2;

    for (int k0 = 0; k0 < K; k0 += 64) {
        *(uint4*)(&As[r * LS + c * 8]) = ra;
        *(uint4*)(&As[(r + 32) * LS + c * 8]) = ra2;
        *(uint4*)(&Bs[r * LS + c * 8]) = rb;
        *(uint4*)(&Bs[(r + 32) * LS + c * 8]) = rb2;
        __syncthreads();
        if (k0 + 64 < K) {
            ra = *(const uint4*)(Ap + k0 + 64);
            ra2 = *(const uint4*)(Ap2 + k0 + 64);
            rb = *(const uint4*)(Bp + k0 + 64);
            rb2 = *(const uint4*)(Bp2 + k0 + 64);
        }
#pragma unroll
        for (int ks = 0; ks < 2; ks++) {
            bf16x8 af[2], bfr[2];
#pragma unroll
            for (int i = 0; i < 2; i++)
                af[i] = *(const bf16x8*)(
                    &As[(wm * 32 + i * 16 + l16) * LS + ks * 32 + quad * 8]);
#pragma unroll
            for (int j = 0; j < 2; j++)
                bfr[j] = *(const bf16x8*)(
                    &Bs[(wn * 32 + j * 16 + l16) * LS + ks * 32 + quad * 8]);
#pragma unroll
            for (int i = 0; i < 2; i++)
#pragma unroll
                for (int j = 0; j < 2; j++)
                    acc[i][j] = __builtin_amdgcn_mfma_f32_16x16x32_bf16(
                        af[i], bfr[j], acc[i][j], 0, 0, 0);
        }
        __syncthreads();
    }

#pragma unroll
    for (int i = 0; i < 2; i++)
#pragma unroll
        for (int j = 0; j < 2; j++) {
            int col = n0 + wn * 32 + j * 16 + l16;
            int rbase = m0 + wm * 32 + i * 16 + quad * 4;
            float bv = (EPI == 2 || EPI == 3) ? bias[col] : 0.f;
#pragma unroll
            for (int rr = 0; rr < 4; rr++) {
                int row = rbase + rr;
                float vv = acc[i][j][rr] + bv;
                if (EPI == 2) vv = 0.5f * vv * (1.f + erff(vv * 0.70710678118654752f));
                if (EPI == 3) vv += resid[(size_t)row * ldc + col];
                if constexpr (sizeof(OutT) == 2)
                    C[(size_t)row * ldc + col] = (OutT)f2bf(vv);
                else
                    C[(size_t)row * ldc + col] = vv;
            }
        }
}

struct GSeg {
    const ushort_t* A; const ushort_t* B; ushort_t* C;
    int lda, ldb, ldc, nx, start;
};

// ---------------------------------------------------------------------------
// proj launch: blocks [0,80) = q/kv_v/kv_a projections; rest = Wproj/W1/W2
// 64x64 transposes backfilling idle CUs.
// ---------------------------------------------------------------------------
__global__ __launch_bounds__(256) void projT_kernel(GSeg s0, GSeg s1, GSeg s2,
                                                    TDesc d0, TDesc d1,
                                                    TDesc d2, int K) {
    __shared__ ushort_t As[64 * 72];
    __shared__ ushort_t Bs[64 * 72];
    int id = blockIdx.x;
    if (id < 80) {
        GSeg s = (id >= s2.start) ? s2 : ((id >= s1.start) ? s1 : s0);
        int t = id - s.start;
        int n0 = (t % s.nx) * 64;
        int m0 = (t / s.nx) * 64;
        gemm64_core<0, ushort_t>(s.A, s.lda, s.B, s.ldb, s.C, s.ldc, nullptr,
                                 nullptr, K, m0, n0, As, Bs);
        return;
    }
    id -= 80;
    TDesc d = (id >= d2.start) ? d2 : ((id >= d1.start) ? d1 : d0);
    transpose_body(d, id - d.start, As);
}

// ---------------------------------------------------------------------------
// Factorized attention body (round-4 layout, verified); LDS passed in.
// ---------------------------------------------------------------------------
DEVFN void attn_body(const ushort_t* __restrict__ q,
                     const ushort_t* __restrict__ kvv,
                     const ushort_t* __restrict__ kva,
                     ushort_t* __restrict__ out, int bh, int qc, float* sm) {
    int b = bh >> 4, h = bh & 15;
    int tid = threadIdx.x;
    float (*Kv)[16] = (float(*)[16])sm;
    float (*Vv)[16] = (float(*)[16])(sm + 64 * 16);
    float (*Ka)[16] = (float(*)[16])(sm + 2 * 64 * 16);
    float (*Va)[16] = (float(*)[16])(sm + 2 * 64 * 16 + 128 * 16);

    {
        int row = tid >> 2, seg = (tid >> 1) & 1, half = tid & 1;
        const ushort_t* src =
            kvv + (size_t)(b * 64 + row) * 512 + seg * 256 + h * 16 + half * 8;
        float* dst = (seg ? Vv[row] : Kv[row]) + half * 8;
        unpack8(*(const uint4*)src, dst);
    }
#pragma unroll
    for (int t2 = 0; t2 < 2; t2++) {
        int t = tid + t2 * 256;
        int row = t >> 2, seg = (t >> 1) & 1, half = t & 1;
        const ushort_t* src =
            kva + (size_t)(b * 128 + row) * 512 + seg * 256 + h * 16 + half * 8;
        float* dst = (seg ? Va[row] : Ka[row]) + half * 8;
        unpack8(*(const uint4*)src, dst);
    }
    __syncthreads();

    int qlocal = tid >> 2;  // 0..63
    int dg = tid & 3;
    int qrow = qc * 64 + qlocal;
    const ushort_t* qp = q + (size_t)(b * 256 + qrow) * 256 + h * 16 + dg * 4;
    uint2 qu = *(const uint2*)qp;
    float4 qv;
    qv.x = __uint_as_float(qu.x << 16) * 0.125f;
    qv.y = __uint_as_float(qu.x & 0xFFFF0000u) * 0.125f;
    qv.z = __uint_as_float(qu.y << 16) * 0.125f;
    qv.w = __uint_as_float(qu.y & 0xFFFF0000u) * 0.125f;

    const float4* Kv4 = (const float4*)Kv;
    const float4* Vv4 = (const float4*)Vv;
    const float4* Ka4 = (const float4*)Ka;
    const float4* Va4 = (const float4*)Va;

    float4 ov = {0.f, 0.f, 0.f, 0.f};
    float den = 0.f;
#pragma unroll 8
    for (int i = 0; i < 64; i++) {
        float4 kk = Kv4[i * 4 + dg];
        float part = qv.x * kk.x + qv.y * kk.y + qv.z * kk.z + qv.w * kk.w;
        part += __shfl_xor(part, 1);
        part += __shfl_xor(part, 2);
        float p = __expf(part);
        den += p;
        float4 vv = Vv4[i * 4 + dg];
        ov.x += p * vv.x; ov.y += p * vv.y; ov.z += p * vv.z; ov.w += p * vv.w;
    }
    float4 oa = {0.f, 0.f, 0.f, 0.f};
    float dena = 0.f;
#pragma unroll 8
    for (int i = 0; i < 128; i++) {
        float4 kk = Ka4[i * 4 + dg];
        float part = qv.x * kk.x + qv.y * kk.y + qv.z * kk.z + qv.w * kk.w;
        part += __shfl_xor(part, 1);
        part += __shfl_xor(part, 2);
        float p = __expf(part);
        dena += p;
        float4 vv = Va4[i * 4 + dg];
        oa.x += p * vv.x; oa.y += p * vv.y; oa.z += p * vv.z; oa.w += p * vv.w;
    }

    float rv = 1.f / den, ra = 1.f / dena;
    union { ushort_t u[4]; uint2 v; } pk;
    pk.u[0] = f2bf(ov.x * rv + oa.x * ra);
    pk.u[1] = f2bf(ov.y * rv + oa.y * ra);
    pk.u[2] = f2bf(ov.z * rv + oa.z * ra);
    pk.u[3] = f2bf(ov.w * rv + oa.w * ra);
    *(uint2*)(out + (size_t)(b * 256 + qrow) * 256 + h * 16 + dg * 4) = pk.v;
}

// mlp2 split-K reduce body: out = sum_z P[z] + b2 + y
DEVFN void reduce_body(const float* __restrict__ P, const float* __restrict__ y,
                       const float* __restrict__ b2, float* __restrict__ out,
                       int blk) {
    int i = blk * 256 + threadIdx.x;
    const float4* p = (const float4*)P;
    float4 a = p[i], b = p[i + 131072], cc = p[i + 2 * 131072],
           d = p[i + 3 * 131072];
    float4 yy = ((const float4*)y)[i];
    float4 bb = ((const float4*)b2)[i & 255];
    float4 o;
    o.x = a.x + b.x + cc.x + d.x + yy.x + bb.x;
    o.y = a.y + b.y + cc.y + d.y + yy.y + bb.y;
    o.z = a.z + b.z + cc.z + d.z + yy.z + bb.z;
    o.w = a.w + b.w + cc.w + d.w + yy.w + bb.w;
    ((float4*)out)[i] = o;
}

// ---------------------------------------------------------------------------
// Cooperative tail: attn -> ygemm -> ln -> mlp1 -> mlp2 -> reduce.
// 512 blocks x 256 thr, LDS union 24 KB, launch_bounds(256,2) => 2 blk/CU
// guaranteed co-residency (= each phase's standalone occupancy).
// ---------------------------------------------------------------------------
struct TailArgs {
    const ushort_t* qout; const ushort_t* kvvb; const ushort_t* kvab;
    ushort_t* attnout;
    const ushort_t* Wprojt; const float* bproj; const float* xmm; float* y;
    const float* ln_mlp_w; const float* ln_mlp_b; ushort_t* h0;
    const ushort_t* W1t; const float* b1; ushort_t* g;
    const ushort_t* W2t; float* P;
    const float* b2; float* outp;
    unsigned int* bars;
};

__global__ __launch_bounds__(256, 2) void tail_kernel(TailArgs a) {
    __shared__ __align__(16) char smem[24576];
    ushort_t* As = (ushort_t*)smem;
    ushort_t* Bs = (ushort_t*)(smem + 9216);
    int bid = blockIdx.x;

    // phase 0: attention (128 tasks)
    if (bid < 128) attn_body(a.qout, a.kvvb, a.kvab, a.attnout, bid & 31,
                             bid >> 5, (float*)smem);
    gsync(&a.bars[0]);

    // phase 1: y = attnout @ Wproj + bproj + xmm (128 tasks, K=256)
    if (bid < 128) {
        int n0 = (bid % 16) * 64, m0 = (bid / 16) * 64;
        gemm64_core<3, float>(a.attnout, 256, a.Wprojt, 256, a.y, 1024,
                              a.bproj, a.xmm, 256, m0, n0, As, Bs);
    }
    gsync(&a.bars[1]);

    // phase 2: h0 = LN(y) (512 tasks)
    ln_body(a.y, a.ln_mlp_w, a.ln_mlp_b, a.h0, bid);
    gsync(&a.bars[2]);

    // phase 3: g = gelu(h0 @ W1 + b1) (512 tasks, K=1024)
    {
        int n0 = (bid % 64) * 64, m0 = (bid / 64) * 64;
        gemm64_core<2, ushort_t>(a.h0, 1024, a.W1t, 1024, a.g, 4096, a.b1,
                                 nullptr, 1024, m0, n0, As, Bs);
    }
    gsync(&a.bars[3]);

    // phase 4: split-K=4: P[z] = g @ W2 slice (512 tasks, K=1024)
    {
        int z = bid >> 7, rr = bid & 127;
        int n0 = (rr % 16) * 64, m0 = (rr / 16) * 64;
        gemm64_core<4, float>(a.g + (size_t)z * 1024, 4096,
                              a.W2t + (size_t)z * 1024, 4096,
                              a.P + (size_t)z * 512 * 1024, 1024, nullptr,
                              nullptr, 1024, m0, n0, As, Bs);
    }
    gsync(&a.bars[4]);

    // phase 5: out = sum P + b2 + y (512 tasks)
    reduce_body(a.P, a.y, a.b2, a.outp, bid);
}

// ---------------------------------------------------------------------------
extern "C" void kernel_launch(void* const* d_in, const int* in_sizes, int n_in,
                              void* d_out, int out_size, void* d_ws,
                              size_t ws_size, hipStream_t stream) {
    const float* xmm = (const float*)d_in[0];
    const float* xv = (const float*)d_in[1];
    const float* xa = (const float*)d_in[2];
    const float* ln_mm_w = (const float*)d_in[3];
    const float* ln_mm_b = (const float*)d_in[4];
    const float* ln_v_w = (const float*)d_in[5];
    const float* ln_v_b = (const float*)d_in[6];
    const float* ln_a_w = (const float*)d_in[7];
    const float* ln_a_b = (const float*)d_in[8];
    const float* Wq = (const float*)d_in[9];
    const float* Wkv = (const float*)d_in[10];
    const float* Wproj = (const float*)d_in[11];
    const float* bproj = (const float*)d_in[12];
    const float* ln_mlp_w = (const float*)d_in[13];
    const float* ln_mlp_b = (const float*)d_in[14];
    const float* W1 = (const float*)d_in[15];
    const float* b1 = (const float*)d_in[16];
    const float* W2 = (const float*)d_in[17];
    const float* b2 = (const float*)d_in[18];
    float* outp = (float*)d_out;

    char* w = (char*)d_ws;
    unsigned int* bars = (unsigned int*)w; w += 256;
    ushort_t* xmmN = (ushort_t*)w;    w += 512 * 1024 * 2;
    ushort_t* xvN = (ushort_t*)w;     w += 128 * 1024 * 2;
    ushort_t* xaN = (ushort_t*)w;     w += 256 * 1024 * 2;
    ushort_t* Wqt = (ushort_t*)w;     w += 256 * 1024 * 2;
    ushort_t* Wkvt = (ushort_t*)w;    w += 512 * 2048 * 2;
    ushort_t* Wprojt = (ushort_t*)w;  w += 1024 * 256 * 2;
    ushort_t* W1t = (ushort_t*)w;     w += 4096 * 1024 * 2;
    ushort_t* W2t = (ushort_t*)w;     w += 1024 * 4096 * 2;
    ushort_t* qout = (ushort_t*)w;    w += 512 * 256 * 2;
    ushort_t* kvvb = (ushort_t*)w;    w += 128 * 512 * 2;
    ushort_t* kvab = (ushort_t*)w;    w += 256 * 512 * 2;
    ushort_t* attnout = (ushort_t*)w; w += 512 * 256 * 2;
    float* y = (float*)w;             w += 512 * 1024 * 4;
    ushort_t* h0 = (ushort_t*)w;      w += 512 * 1024 * 2;
    ushort_t* g = (ushort_t*)w;       w += 512 * 4096 * 2;
    float* P = (float*)w;             w += 4 * 512 * 1024 * 4;

    // zero the 5 barrier counters (captured as a memset node per replay)
    hipMemsetAsync(bars, 0, 64, stream);

    // 1) prep: 3 LayerNorms + Wq/Wkv transposes (64+256 tiles of 64x64)
    LNSeg L0{xmm, ln_mm_w, ln_mm_b, xmmN, 0};
    LNSeg L1{xv, ln_v_w, ln_v_b, xvN, 512};
    LNSeg L2{xa, ln_a_w, ln_a_b, xaN, 640};
    TDesc TQ{Wq, Wqt, 1024, 256, 4, 0};       // 16x4 = 64 tiles
    TDesc TKV{Wkv, Wkvt, 2048, 512, 8, 64};   // 32x8 = 256 tiles
    prep_kernel<<<896 + 320, 256, 0, stream>>>(L0, L1, L2, TQ, TKV);

    // 2) projections (80 blocks) + Wproj/W1/W2 transposes (2112 blocks)
    GSeg G0{xmmN, Wqt, qout, 1024, 1024, 256, 4, 0};
    GSeg G1{xvN, Wkvt, kvvb, 1024, 2048, 512, 8, 32};
    GSeg G2{xaN, Wkvt + 1024, kvab, 1024, 2048, 512, 8, 48};
    TDesc TP{Wproj, Wprojt, 256, 1024, 16, 0};    // 4x16 = 64 tiles
    TDesc T1{W1, W1t, 1024, 4096, 64, 64};        // 16x64 = 1024 tiles
    TDesc T2{W2, W2t, 4096, 1024, 16, 1088};      // 64x16 = 1024 tiles
    projT_kernel<<<80 + 2112, 256, 0, stream>>>(G0, G1, G2, TP, T1, T2, 1024);

    // 3) cooperative tail: attn -> ygemm -> ln -> mlp1 -> mlp2 -> reduce
    TailArgs TA{qout, kvvb, kvab, attnout,
                Wprojt, bproj, xmm, y,
                ln_mlp_w, ln_mlp_b, h0,
                W1t, b1, g,
                W2t, P,
                b2, outp, bars};
    tail_kernel<<<512, 256, 0, stream>>>(TA);

    (void)in_sizes; (void)n_in; (void)out_size; (void)ws_size;
}

// Round 7
// 224.046 us; speedup vs baseline: 2.2872x; 2.2872x over previous
//
#include <hip/hip_runtime.h>
#include <hip/hip_bf16.h>
#include <math.h>

// ---------------------------------------------------------------------------
// FusionBlock_DenseAVInteractions — round 11
//
// Round-10 post-mortem: cooperative tail = 385 us for ~30 us of work at the
// CORRECT per-phase occupancy -> the gsync spin-barrier itself is the poison
// (512 blocks polling one device-scope line across 8 XCDs). Rule: no
// spin-barriers on MI355X. Non-polling device-scope patterns are fine.
//
// Round-11 (from the 184.2 us round-9 baseline): remove 2 launches without
// any barrier:
//  * ln launch removed: ygemm epilogue emits per-block per-row (sum,sum^2)
//    partials to pstats[16][512][2] (deterministic slots, no atomics);
//    mlp1 combines 16 partials/row, derives mean/rstd, and normalizes y
//    during A-staging (round-6-verified staging). h0 buffer gone.
//  * reduce launch removed: mlp2's 4 split-K blocks per tile do
//    threadfence + one atomicAdd on a per-tile counter (4 contenders, no
//    polling); the old==3 arrival sums the 4 P slices + y + b2 -> out.
//    Counters zeroed by attn block 0 (earlier launch = ordered).
// 8 launches -> 6. Everything else byte-identical to round-9.
// ---------------------------------------------------------------------------

typedef unsigned short ushort_t;
typedef __attribute__((ext_vector_type(8))) __bf16 bf16x8;
typedef __attribute__((ext_vector_type(4))) float f32x4;

#define DEVFN static __device__ __forceinline__

DEVFN ushort_t f2bf(float f) {
    unsigned int x = __float_as_uint(f);
    unsigned int r = x + 0x7FFFu + ((x >> 16) & 1u);  // RNE
    return (ushort_t)(r >> 16);
}
// unpack 8 bf16 (uint4) -> 8 floats
DEVFN void unpack8(uint4 dv, float* dst) {
    unsigned int ws[4] = {dv.x, dv.y, dv.z, dv.w};
#pragma unroll
    for (int i = 0; i < 4; i++) {
        dst[2 * i] = __uint_as_float(ws[i] << 16);
        dst[2 * i + 1] = __uint_as_float(ws[i] & 0xFFFF0000u);
    }
}

// ---------------------------------------------------------------------------
// LayerNorm body (prep): one 256-thread block per row of 1024.
// ---------------------------------------------------------------------------
DEVFN void ln_body(const float* __restrict__ x, const float* __restrict__ w,
                   const float* __restrict__ b, ushort_t* __restrict__ out,
                   int row) {
    const float4* xr4 = (const float4*)(x + (size_t)row * 1024);
    ushort_t* orow = out + (size_t)row * 1024;
    int tid = threadIdx.x;
    float4 v4 = xr4[tid];
    float s = v4.x + v4.y + v4.z + v4.w;
    float ss = v4.x * v4.x + v4.y * v4.y + v4.z * v4.z + v4.w * v4.w;
#pragma unroll
    for (int off = 32; off > 0; off >>= 1) {
        s += __shfl_down(s, off);
        ss += __shfl_down(ss, off);
    }
    __shared__ float red[8];
    if ((tid & 63) == 0) {
        red[tid >> 6] = s;
        red[4 + (tid >> 6)] = ss;
    }
    __syncthreads();
    s = red[0] + red[1] + red[2] + red[3];
    ss = red[4] + red[5] + red[6] + red[7];
    float mean = s * (1.f / 1024.f);
    float var = ss * (1.f / 1024.f) - mean * mean;
    float rstd = rsqrtf(var + 1e-5f);
    const float4 w4 = ((const float4*)w)[tid];
    const float4 b4 = ((const float4*)b)[tid];
    union { ushort_t u[4]; uint2 v; } pk;
    pk.u[0] = f2bf((v4.x - mean) * rstd * w4.x + b4.x);
    pk.u[1] = f2bf((v4.y - mean) * rstd * w4.y + b4.y);
    pk.u[2] = f2bf((v4.z - mean) * rstd * w4.z + b4.z);
    pk.u[3] = f2bf((v4.w - mean) * rstd * w4.w + b4.w);
    *(uint2*)(&orow[tid * 4]) = pk.v;
}

struct LNSeg {
    const float* x; const float* w; const float* b; ushort_t* out; int start;
};
struct TDesc { const float* in; ushort_t* out; int R, C, nx, start; };

// ---------------------------------------------------------------------------
// 64x64 transpose tile (fp32 [R,C] -> bf16 [C,R]), vectorized (round-9).
// ---------------------------------------------------------------------------
DEVFN void transpose_body(TDesc d, int t, ushort_t* lds) {
    int bx = (t % d.nx) * 64;
    int by = (t / d.nx) * 64;
    int tid = threadIdx.x;
#pragma unroll
    for (int it = 0; it < 4; it++) {
        int idx = it * 256 + tid;        // 0..1023
        int r = idx >> 4;                // 0..63
        int c4 = (idx & 15) << 2;        // 0,4,...,60
        float4 v = *(const float4*)(&d.in[(size_t)(by + r) * d.C + bx + c4]);
        float vals[4] = {v.x, v.y, v.z, v.w};
#pragma unroll
        for (int j = 0; j < 4; j++) {
            int c = c4 + j;
            int rs = (r + (((c >> 2) & 7) << 3)) & 63;
            lds[c * 64 + rs] = f2bf(vals[j]);
        }
    }
    __syncthreads();
#pragma unroll
    for (int it = 0; it < 2; it++) {
        int idx = it * 256 + tid;        // 0..511
        int c = idx >> 3;                // 0..63
        int l8 = idx & 7;
        int rs = ((l8 << 3) + (((c >> 2) & 7) << 3)) & 63;
        uint4 val = *(const uint4*)(&lds[c * 64 + rs]);
        *(uint4*)(&d.out[(size_t)(bx + c) * d.R + by + (l8 << 3)]) = val;
    }
    __syncthreads();  // safe LDS reuse by caller
}

// ---------------------------------------------------------------------------
// prep: blocks [0,896) = 3 LayerNorms; rest = Wq/Wkv transposes.
// ---------------------------------------------------------------------------
__global__ __launch_bounds__(256) void prep_kernel(LNSeg l0, LNSeg l1,
                                                   LNSeg l2, TDesc d0,
                                                   TDesc d1) {
    int id = blockIdx.x;
    if (id < 896) {
        LNSeg s = (id >= l2.start) ? l2 : ((id >= l1.start) ? l1 : l0);
        ln_body(s.x, s.w, s.b, s.out, id - s.start);
        return;
    }
    id -= 896;
    __shared__ ushort_t tile[64 * 64];
    TDesc d = (id >= d1.start) ? d1 : d0;
    transpose_body(d, id - d.start, tile);
}

// ---------------------------------------------------------------------------
// Pipelined MFMA bf16 GEMM core, BK=64: 64x64 tile, 256 threads (2x2 waves),
// LS=72. EPI: 0 = bf16 store; 4 = raw fp32 store (split-K partial);
// 5 = +bias +resid fp32 store AND per-row (sum,sum^2) partials -> stats
//     (stats = pstats + bx*512*2; deterministic slots, no atomics).
// ---------------------------------------------------------------------------
template <int EPI, typename OutT>
DEVFN void gemm64_core(const ushort_t* __restrict__ A, int lda,
                       const ushort_t* __restrict__ B, int ldb,
                       OutT* __restrict__ C, int ldc,
                       const float* __restrict__ bias,
                       const float* __restrict__ resid, int K, int m0, int n0,
                       ushort_t* As, ushort_t* Bs,
                       float* __restrict__ stats = nullptr) {
    constexpr int LS = 72;
    int tid = threadIdx.x;
    int wave = tid >> 6, lane = tid & 63;
    int wm = wave >> 1, wn = wave & 1;
    int quad = lane >> 4, l16 = lane & 15;

    f32x4 acc[2][2];
#pragma unroll
    for (int i = 0; i < 2; i++)
#pragma unroll
        for (int j = 0; j < 2; j++) acc[i][j] = (f32x4){0.f, 0.f, 0.f, 0.f};

    int r = tid >> 3;  // 0..31
    int c = tid & 7;   // k-chunk of 8 bf16
    const ushort_t* Ap = A + (size_t)(m0 + r) * lda + c * 8;
    const ushort_t* Bp = B + (size_t)(n0 + r) * ldb + c * 8;
    const ushort_t* Ap2 = Ap + (size_t)32 * lda;
    const ushort_t* Bp2 = Bp + (size_t)32 * ldb;
    uint4 ra = *(const uint4*)Ap, ra2 = *(const uint4*)Ap2;
    uint4 rb = *(const uint4*)Bp, rb2 = *(const uint4*)Bp2;

    for (int k0 = 0; k0 < K; k0 += 64) {
        *(uint4*)(&As[r * LS + c * 8]) = ra;
        *(uint4*)(&As[(r + 32) * LS + c * 8]) = ra2;
        *(uint4*)(&Bs[r * LS + c * 8]) = rb;
        *(uint4*)(&Bs[(r + 32) * LS + c * 8]) = rb2;
        __syncthreads();
        if (k0 + 64 < K) {
            ra = *(const uint4*)(Ap + k0 + 64);
            ra2 = *(const uint4*)(Ap2 + k0 + 64);
            rb = *(const uint4*)(Bp + k0 + 64);
            rb2 = *(const uint4*)(Bp2 + k0 + 64);
        }
#pragma unroll
        for (int ks = 0; ks < 2; ks++) {
            bf16x8 af[2], bfr[2];
#pragma unroll
            for (int i = 0; i < 2; i++)
                af[i] = *(const bf16x8*)(
                    &As[(wm * 32 + i * 16 + l16) * LS + ks * 32 + quad * 8]);
#pragma unroll
            for (int j = 0; j < 2; j++)
                bfr[j] = *(const bf16x8*)(
                    &Bs[(wn * 32 + j * 16 + l16) * LS + ks * 32 + quad * 8]);
#pragma unroll
            for (int i = 0; i < 2; i++)
#pragma unroll
                for (int j = 0; j < 2; j++)
                    acc[i][j] = __builtin_amdgcn_mfma_f32_16x16x32_bf16(
                        af[i], bfr[j], acc[i][j], 0, 0, 0);
        }
        __syncthreads();
    }

    float srow[2][4] = {{0.f, 0.f, 0.f, 0.f}, {0.f, 0.f, 0.f, 0.f}};
    float ssrow[2][4] = {{0.f, 0.f, 0.f, 0.f}, {0.f, 0.f, 0.f, 0.f}};

#pragma unroll
    for (int i = 0; i < 2; i++)
#pragma unroll
        for (int j = 0; j < 2; j++) {
            int col = n0 + wn * 32 + j * 16 + l16;
            int rbase = m0 + wm * 32 + i * 16 + quad * 4;
            float bv = (EPI == 5) ? bias[col] : 0.f;
#pragma unroll
            for (int rr = 0; rr < 4; rr++) {
                int row = rbase + rr;
                float vv = acc[i][j][rr] + bv;
                if constexpr (EPI == 5) {
                    vv += resid[(size_t)row * ldc + col];
                    srow[i][rr] += vv;
                    ssrow[i][rr] += vv * vv;
                }
                if constexpr (sizeof(OutT) == 2)
                    C[(size_t)row * ldc + col] = (OutT)f2bf(vv);
                else
                    C[(size_t)row * ldc + col] = vv;
            }
        }

    if constexpr (EPI == 5) {
        // cross-lane reduce over l16 (32 cols per wave incl. j), then
        // cross-wave combine via LDS (reuse As; free after K-loop barrier).
        float* ls = (float*)As;  // [64 rows][2 wn][2 stats]
#pragma unroll
        for (int i = 0; i < 2; i++)
#pragma unroll
            for (int rr = 0; rr < 4; rr++) {
                float s = srow[i][rr], ss = ssrow[i][rr];
#pragma unroll
                for (int m = 1; m < 16; m <<= 1) {
                    s += __shfl_xor(s, m);
                    ss += __shfl_xor(ss, m);
                }
                if (l16 == 0) {
                    int rl = wm * 32 + i * 16 + quad * 4 + rr;  // 0..63
                    ls[rl * 4 + wn * 2 + 0] = s;
                    ls[rl * 4 + wn * 2 + 1] = ss;
                }
            }
        __syncthreads();
        if (tid < 64) {
            float s = ls[tid * 4 + 0] + ls[tid * 4 + 2];
            float ss = ls[tid * 4 + 1] + ls[tid * 4 + 3];
            stats[(size_t)(m0 + tid) * 2 + 0] = s;
            stats[(size_t)(m0 + tid) * 2 + 1] = ss;
        }
    }
}

struct GSeg {
    const ushort_t* A; const ushort_t* B; ushort_t* C;
    int lda, ldb, ldc, nx, start;
};

// ---------------------------------------------------------------------------
// proj launch: blocks [0,80) = q/kv_v/kv_a projections; rest = Wproj/W1/W2
// transposes backfilling idle CUs.
// ---------------------------------------------------------------------------
__global__ __launch_bounds__(256) void projT_kernel(GSeg s0, GSeg s1, GSeg s2,
                                                    TDesc d0, TDesc d1,
                                                    TDesc d2, int K) {
    __shared__ ushort_t As[64 * 72];
    __shared__ ushort_t Bs[64 * 72];
    int id = blockIdx.x;
    if (id < 80) {
        GSeg s = (id >= s2.start) ? s2 : ((id >= s1.start) ? s1 : s0);
        int t = id - s.start;
        int n0 = (t % s.nx) * 64;
        int m0 = (t / s.nx) * 64;
        gemm64_core<0, ushort_t>(s.A, s.lda, s.B, s.ldb, s.C, s.ldc, nullptr,
                                 nullptr, K, m0, n0, As, Bs);
        return;
    }
    id -= 80;
    TDesc d = (id >= d2.start) ? d2 : ((id >= d1.start) ? d1 : d0);
    transpose_body(d, id - d.start, As);
}

// ---------------------------------------------------------------------------
// ygemm: y = attnout @ Wproj + bproj + xmm (fp32) + per-row stats partials.
// grid (16 n-tiles, 8 m-bands).
// ---------------------------------------------------------------------------
__global__ __launch_bounds__(256) void ygemm_kernel(
    const ushort_t* __restrict__ A, const ushort_t* __restrict__ Bt,
    float* __restrict__ y, const float* __restrict__ bproj,
    const float* __restrict__ xmm, float* __restrict__ pstats) {
    __shared__ ushort_t As[64 * 72];
    __shared__ ushort_t Bs[64 * 72];
    gemm64_core<5, float>(A, 256, Bt, 256, y, 1024, bproj, xmm, 256,
                          blockIdx.y * 64, blockIdx.x * 64, As, Bs,
                          pstats + (size_t)blockIdx.x * 512 * 2);
}

// ---------------------------------------------------------------------------
// mlp1 with fused LN: g = gelu(LN(y) @ W1 + b1), bf16. Stats from pstats
// (16 partials per row, summed deterministically). Round-6-verified BK=32
// staging: normalize fp32 y -> bf16 during A-staging.
// ---------------------------------------------------------------------------
__global__ __launch_bounds__(256) void mlp1_kernel(
    const float* __restrict__ y, const float* __restrict__ pstats,
    const float* __restrict__ lnw, const float* __restrict__ lnb,
    const ushort_t* __restrict__ W1t, const float* __restrict__ b1,
    ushort_t* __restrict__ g) {
    constexpr int LS = 40;
    __shared__ ushort_t As[64 * LS];
    __shared__ ushort_t Bs[64 * LS];
    __shared__ float wls[1024], bls[1024];
    int tid = threadIdx.x;
    int m0 = blockIdx.y * 64, n0 = blockIdx.x * 64;

    ((float4*)wls)[tid] = ((const float4*)lnw)[tid];
    ((float4*)bls)[tid] = ((const float4*)lnb)[tid];

    // stats for this thread's staging row r = tid>>2 (4 lanes per row each
    // sum 4 of the 16 n-block partials, then quad shfl combine)
    int r = tid >> 2, c = tid & 3;
    float s = 0.f, ss = 0.f;
#pragma unroll
    for (int k = 0; k < 4; k++) {
        size_t o = ((size_t)(c * 4 + k) * 512 + (m0 + r)) * 2;
        s += pstats[o];
        ss += pstats[o + 1];
    }
    s += __shfl_xor(s, 1); ss += __shfl_xor(ss, 1);
    s += __shfl_xor(s, 2); ss += __shfl_xor(ss, 2);
    float mr = s * (1.f / 1024.f);
    float var = ss * (1.f / 1024.f) - mr * mr;
    float rs = rsqrtf(var + 1e-5f);

    int wave = tid >> 6, lane = tid & 63;
    int wm = wave >> 1, wn = wave & 1;
    int quad = lane >> 4, l16 = lane & 15;

    f32x4 acc[2][2];
#pragma unroll
    for (int i = 0; i < 2; i++)
#pragma unroll
        for (int j = 0; j < 2; j++) acc[i][j] = (f32x4){0.f, 0.f, 0.f, 0.f};

    const float* Ay = y + (size_t)(m0 + r) * 1024 + c * 8;
    const ushort_t* Bp = W1t + (size_t)(n0 + r) * 1024 + c * 8;
    float4 ya0 = *(const float4*)Ay;
    float4 ya1 = *(const float4*)(Ay + 4);
    uint4 rb = *(const uint4*)Bp;
    __syncthreads();  // wls/bls ready

    for (int k0 = 0; k0 < 1024; k0 += 32) {
        float4 w0 = *(const float4*)&wls[k0 + c * 8];
        float4 w1 = *(const float4*)&wls[k0 + c * 8 + 4];
        float4 bb0 = *(const float4*)&bls[k0 + c * 8];
        float4 bb1 = *(const float4*)&bls[k0 + c * 8 + 4];
        union { ushort_t u[8]; uint4 v; } pa;
        pa.u[0] = f2bf((ya0.x - mr) * rs * w0.x + bb0.x);
        pa.u[1] = f2bf((ya0.y - mr) * rs * w0.y + bb0.y);
        pa.u[2] = f2bf((ya0.z - mr) * rs * w0.z + bb0.z);
        pa.u[3] = f2bf((ya0.w - mr) * rs * w0.w + bb0.w);
        pa.u[4] = f2bf((ya1.x - mr) * rs * w1.x + bb1.x);
        pa.u[5] = f2bf((ya1.y - mr) * rs * w1.y + bb1.y);
        pa.u[6] = f2bf((ya1.z - mr) * rs * w1.z + bb1.z);
        pa.u[7] = f2bf((ya1.w - mr) * rs * w1.w + bb1.w);
        *(uint4*)(&As[r * LS + c * 8]) = pa.v;
        *(uint4*)(&Bs[r * LS + c * 8]) = rb;
        __syncthreads();
        if (k0 + 32 < 1024) {
            ya0 = *(const float4*)(Ay + k0 + 32);
            ya1 = *(const float4*)(Ay + k0 + 36);
            rb = *(const uint4*)(Bp + k0 + 32);
        }
        bf16x8 af[2], bfr[2];
#pragma unroll
        for (int i = 0; i < 2; i++)
            af[i] = *(const bf16x8*)(&As[(wm * 32 + i * 16 + l16) * LS + quad * 8]);
#pragma unroll
        for (int j = 0; j < 2; j++)
            bfr[j] = *(const bf16x8*)(&Bs[(wn * 32 + j * 16 + l16) * LS + quad * 8]);
#pragma unroll
        for (int i = 0; i < 2; i++)
#pragma unroll
            for (int j = 0; j < 2; j++)
                acc[i][j] = __builtin_amdgcn_mfma_f32_16x16x32_bf16(
                    af[i], bfr[j], acc[i][j], 0, 0, 0);
        __syncthreads();
    }

#pragma unroll
    for (int i = 0; i < 2; i++)
#pragma unroll
        for (int j = 0; j < 2; j++) {
            int col = n0 + wn * 32 + j * 16 + l16;
            int rbase = m0 + wm * 32 + i * 16 + quad * 4;
            float bv = b1[col];
#pragma unroll
            for (int rr = 0; rr < 4; rr++) {
                int row = rbase + rr;
                float vv = acc[i][j][rr] + bv;
                vv = 0.5f * vv * (1.f + erff(vv * 0.70710678118654752f));
                g[(size_t)row * 4096 + col] = f2bf(vv);
            }
        }
}

// ---------------------------------------------------------------------------
// mlp2: split-K=4 P[z] = g @ W2 slice; last-arriving block per output tile
// (non-polling atomic counter, 4 contenders) sums the 4 slices + y + b2 ->
// out. Counters zeroed by attn (earlier launch).
// ---------------------------------------------------------------------------
__global__ __launch_bounds__(256) void mlp2_kernel(
    const ushort_t* __restrict__ g, const ushort_t* __restrict__ W2t,
    float* __restrict__ P, const float* __restrict__ y,
    const float* __restrict__ b2, float* __restrict__ out,
    unsigned int* __restrict__ cnt) {
    __shared__ ushort_t As[64 * 72];
    __shared__ ushort_t Bs[64 * 72];
    int z = blockIdx.z;
    int m0 = blockIdx.y * 64, n0 = blockIdx.x * 64;
    gemm64_core<4, float>(g + (size_t)z * 1024, 4096, W2t + (size_t)z * 1024,
                          4096, P + (size_t)z * 512 * 1024, 1024, nullptr,
                          nullptr, 1024, m0, n0, As, Bs);

    __shared__ int lastf;
    __syncthreads();  // all threads' P stores drained (vmcnt(0) at barrier)
    if (threadIdx.x == 0) {
        __threadfence();  // release: P visible device-wide
        unsigned int old = __hip_atomic_fetch_add(
            &cnt[blockIdx.y * 16 + blockIdx.x], 1u, __ATOMIC_ACQ_REL,
            __HIP_MEMORY_SCOPE_AGENT);
        lastf = (old == 3u);
        if (lastf) __threadfence();  // acquire: others' P readable
    }
    __syncthreads();
    if (!lastf) return;

    int tid = threadIdx.x;
#pragma unroll
    for (int k = 0; k < 4; k++) {
        int idx4 = tid * 4 + k;            // float4 slot 0..1023
        int row = m0 + (idx4 >> 4);        // 16 float4 per 64-col row
        int c0 = n0 + (idx4 & 15) * 4;
        size_t off = (size_t)row * 1024 + c0;
        float4 a = *(const float4*)(P + off);
        float4 b = *(const float4*)(P + 524288 + off);
        float4 cc = *(const float4*)(P + 1048576 + off);
        float4 d = *(const float4*)(P + 1572864 + off);
        float4 yy = *(const float4*)(y + off);
        float4 bb = *(const float4*)(b2 + c0);
        float4 o;
        o.x = a.x + b.x + cc.x + d.x + yy.x + bb.x;
        o.y = a.y + b.y + cc.y + d.y + yy.y + bb.y;
        o.z = a.z + b.z + cc.z + d.z + yy.z + bb.z;
        o.w = a.w + b.w + cc.w + d.w + yy.w + bb.w;
        *(float4*)(out + off) = o;
    }
}

// ---------------------------------------------------------------------------
// Factorized attention (round-4 layout, verified). Block 0 additionally
// zeroes the mlp2 tile counters (used 3 launches later; stream-ordered).
// ---------------------------------------------------------------------------
__global__ __launch_bounds__(256) void attn_kernel(
    const ushort_t* __restrict__ q, const ushort_t* __restrict__ kvv,
    const ushort_t* __restrict__ kva, ushort_t* __restrict__ out,
    unsigned int* __restrict__ cnt) {
    if (blockIdx.x == 0 && blockIdx.y == 0 && threadIdx.x < 128)
        cnt[threadIdx.x] = 0u;

    int bh = blockIdx.x;
    int b = bh >> 4, h = bh & 15;
    int tid = threadIdx.x;

    __shared__ float Kv[64][16], Vv[64][16], Ka[128][16], Va[128][16];

    {
        int row = tid >> 2, seg = (tid >> 1) & 1, half = tid & 1;
        const ushort_t* src =
            kvv + (size_t)(b * 64 + row) * 512 + seg * 256 + h * 16 + half * 8;
        float* dst = (seg ? Vv[row] : Kv[row]) + half * 8;
        unpack8(*(const uint4*)src, dst);
    }
#pragma unroll
    for (int t2 = 0; t2 < 2; t2++) {
        int t = tid + t2 * 256;
        int row = t >> 2, seg = (t >> 1) & 1, half = t & 1;
        const ushort_t* src =
            kva + (size_t)(b * 128 + row) * 512 + seg * 256 + h * 16 + half * 8;
        float* dst = (seg ? Va[row] : Ka[row]) + half * 8;
        unpack8(*(const uint4*)src, dst);
    }
    __syncthreads();

    int qlocal = tid >> 2;  // 0..63
    int dg = tid & 3;
    int qrow = blockIdx.y * 64 + qlocal;
    const ushort_t* qp = q + (size_t)(b * 256 + qrow) * 256 + h * 16 + dg * 4;
    uint2 qu = *(const uint2*)qp;
    float4 qv;
    qv.x = __uint_as_float(qu.x << 16) * 0.125f;
    qv.y = __uint_as_float(qu.x & 0xFFFF0000u) * 0.125f;
    qv.z = __uint_as_float(qu.y << 16) * 0.125f;
    qv.w = __uint_as_float(qu.y & 0xFFFF0000u) * 0.125f;

    const float4* Kv4 = (const float4*)Kv;
    const float4* Vv4 = (const float4*)Vv;
    const float4* Ka4 = (const float4*)Ka;
    const float4* Va4 = (const float4*)Va;

    float4 ov = {0.f, 0.f, 0.f, 0.f};
    float den = 0.f;
#pragma unroll 8
    for (int i = 0; i < 64; i++) {
        float4 kk = Kv4[i * 4 + dg];
        float part = qv.x * kk.x + qv.y * kk.y + qv.z * kk.z + qv.w * kk.w;
        part += __shfl_xor(part, 1);
        part += __shfl_xor(part, 2);
        float p = __expf(part);
        den += p;
        float4 vv = Vv4[i * 4 + dg];
        ov.x += p * vv.x; ov.y += p * vv.y; ov.z += p * vv.z; ov.w += p * vv.w;
    }
    float4 oa = {0.f, 0.f, 0.f, 0.f};
    float dena = 0.f;
#pragma unroll 8
    for (int i = 0; i < 128; i++) {
        float4 kk = Ka4[i * 4 + dg];
        float part = qv.x * kk.x + qv.y * kk.y + qv.z * kk.z + qv.w * kk.w;
        part += __shfl_xor(part, 1);
        part += __shfl_xor(part, 2);
        float p = __expf(part);
        dena += p;
        float4 vv = Va4[i * 4 + dg];
        oa.x += p * vv.x; oa.y += p * vv.y; oa.z += p * vv.z; oa.w += p * vv.w;
    }

    float rv = 1.f / den, ra = 1.f / dena;
    union { ushort_t u[4]; uint2 v; } pk;
    pk.u[0] = f2bf(ov.x * rv + oa.x * ra);
    pk.u[1] = f2bf(ov.y * rv + oa.y * ra);
    pk.u[2] = f2bf(ov.z * rv + oa.z * ra);
    pk.u[3] = f2bf(ov.w * rv + oa.w * ra);
    *(uint2*)(out + (size_t)(b * 256 + qrow) * 256 + h * 16 + dg * 4) = pk.v;
}

// ---------------------------------------------------------------------------
extern "C" void kernel_launch(void* const* d_in, const int* in_sizes, int n_in,
                              void* d_out, int out_size, void* d_ws,
                              size_t ws_size, hipStream_t stream) {
    const float* xmm = (const float*)d_in[0];
    const float* xv = (const float*)d_in[1];
    const float* xa = (const float*)d_in[2];
    const float* ln_mm_w = (const float*)d_in[3];
    const float* ln_mm_b = (const float*)d_in[4];
    const float* ln_v_w = (const float*)d_in[5];
    const float* ln_v_b = (const float*)d_in[6];
    const float* ln_a_w = (const float*)d_in[7];
    const float* ln_a_b = (const float*)d_in[8];
    const float* Wq = (const float*)d_in[9];
    const float* Wkv = (const float*)d_in[10];
    const float* Wproj = (const float*)d_in[11];
    const float* bproj = (const float*)d_in[12];
    const float* ln_mlp_w = (const float*)d_in[13];
    const float* ln_mlp_b = (const float*)d_in[14];
    const float* W1 = (const float*)d_in[15];
    const float* b1 = (const float*)d_in[16];
    const float* W2 = (const float*)d_in[17];
    const float* b2 = (const float*)d_in[18];
    float* outp = (float*)d_out;

    char* w = (char*)d_ws;
    unsigned int* cnt = (unsigned int*)w; w += 1024;           // 128 used
    float* pstats = (float*)w;        w += 16 * 512 * 2 * 4;   // 64 KB
    ushort_t* xmmN = (ushort_t*)w;    w += 512 * 1024 * 2;
    ushort_t* xvN = (ushort_t*)w;     w += 128 * 1024 * 2;
    ushort_t* xaN = (ushort_t*)w;     w += 256 * 1024 * 2;
    ushort_t* Wqt = (ushort_t*)w;     w += 256 * 1024 * 2;
    ushort_t* Wkvt = (ushort_t*)w;    w += 512 * 2048 * 2;
    ushort_t* Wprojt = (ushort_t*)w;  w += 1024 * 256 * 2;
    ushort_t* W1t = (ushort_t*)w;     w += 4096 * 1024 * 2;
    ushort_t* W2t = (ushort_t*)w;     w += 1024 * 4096 * 2;
    ushort_t* qout = (ushort_t*)w;    w += 512 * 256 * 2;
    ushort_t* kvvb = (ushort_t*)w;    w += 128 * 512 * 2;
    ushort_t* kvab = (ushort_t*)w;    w += 256 * 512 * 2;
    ushort_t* attnout = (ushort_t*)w; w += 512 * 256 * 2;
    float* y = (float*)w;             w += 512 * 1024 * 4;
    ushort_t* g = (ushort_t*)w;       w += 512 * 4096 * 2;
    float* P = (float*)w;             w += 4 * 512 * 1024 * 4;

    // 1) prep: 3 LayerNorms + Wq/Wkv transposes
    LNSeg L0{xmm, ln_mm_w, ln_mm_b, xmmN, 0};
    LNSeg L1{xv, ln_v_w, ln_v_b, xvN, 512};
    LNSeg L2{xa, ln_a_w, ln_a_b, xaN, 640};
    TDesc TQ{Wq, Wqt, 1024, 256, 4, 0};       // 64 tiles
    TDesc TKV{Wkv, Wkvt, 2048, 512, 8, 64};   // 256 tiles
    prep_kernel<<<896 + 320, 256, 0, stream>>>(L0, L1, L2, TQ, TKV);

    // 2) projections (80) + Wproj/W1/W2 transposes (2112)
    GSeg G0{xmmN, Wqt, qout, 1024, 1024, 256, 4, 0};
    GSeg G1{xvN, Wkvt, kvvb, 1024, 2048, 512, 8, 32};
    GSeg G2{xaN, Wkvt + 1024, kvab, 1024, 2048, 512, 8, 48};
    TDesc TP{Wproj, Wprojt, 256, 1024, 16, 0};    // 64 tiles
    TDesc T1{W1, W1t, 1024, 4096, 64, 64};        // 1024 tiles
    TDesc T2{W2, W2t, 4096, 1024, 16, 1088};      // 1024 tiles
    projT_kernel<<<80 + 2112, 256, 0, stream>>>(G0, G1, G2, TP, T1, T2, 1024);

    // 3) factorized attention (+ zero mlp2 counters)
    attn_kernel<<<dim3(32, 4), 256, 0, stream>>>(qout, kvvb, kvab, attnout,
                                                 cnt);

    // 4) y = attnout @ Wproj + bproj + xmm (fp32) + LN stats partials
    ygemm_kernel<<<dim3(16, 8), 256, 0, stream>>>(attnout, Wprojt, y, bproj,
                                                  xmm, pstats);

    // 5) g = gelu(LN(y) @ W1 + b1)  (LN fused via pstats)
    mlp1_kernel<<<dim3(64, 8), 256, 0, stream>>>(y, pstats, ln_mlp_w,
                                                 ln_mlp_b, W1t, b1, g);

    // 6) split-K=4 mlp2 + last-block tile reduction -> out
    mlp2_kernel<<<dim3(16, 8, 4), 256, 0, stream>>>(g, W2t, P, y, b2, outp,
                                                    cnt);

    (void)in_sizes; (void)n_in; (void)out_size; (void)ws_size;
}

// Round 8
// 189.121 us; speedup vs baseline: 2.7096x; 1.1847x over previous
//
#include <hip/hip_runtime.h>
#include <hip/hip_bf16.h>
#include <math.h>

// ---------------------------------------------------------------------------
// FusionBlock_DenseAVInteractions — round 12
//
// Round-11 post-mortem: mlp2-with-acquire-fence = 52.5 us (vs ~16 for
// mlp2+reduce): device-scope acquire threadfence invalidates the XCD L2 and
// poisons co-resident blocks' reads. Rule: no device-scope fences in hot
// kernels (alongside round-10's no-spin-barriers). Gap back-calc says launch
// boundaries are ~3 us, and round-11's mlp1 regression was the BK=32
// confound, NOT the pstats LN fusion (which verified bit-exact).
//
// Round-12 = round-9 base (184.2 verified) +
//  * ygemm EPI=5: per-row (sum,sum^2) partials -> pstats (round-11-verified)
//  * mlp1: BK=64/LS=72 core (round-9's) with LN fused via pstats
//    (meanv/rstdv pre-pass in LDS, normalize during A-staging)
//  * ln launch + h0 buffer removed. 8 launches -> 7.
//  * mlp2 + reduce: round-9 verbatim (no fences, no atomics).
// ---------------------------------------------------------------------------

typedef unsigned short ushort_t;
typedef __attribute__((ext_vector_type(8))) __bf16 bf16x8;
typedef __attribute__((ext_vector_type(4))) float f32x4;

#define DEVFN static __device__ __forceinline__

DEVFN ushort_t f2bf(float f) {
    unsigned int x = __float_as_uint(f);
    unsigned int r = x + 0x7FFFu + ((x >> 16) & 1u);  // RNE
    return (ushort_t)(r >> 16);
}
// unpack 8 bf16 (uint4) -> 8 floats
DEVFN void unpack8(uint4 dv, float* dst) {
    unsigned int ws[4] = {dv.x, dv.y, dv.z, dv.w};
#pragma unroll
    for (int i = 0; i < 4; i++) {
        dst[2 * i] = __uint_as_float(ws[i] << 16);
        dst[2 * i + 1] = __uint_as_float(ws[i] & 0xFFFF0000u);
    }
}

// ---------------------------------------------------------------------------
// LayerNorm body (prep): one 256-thread block per row of 1024.
// ---------------------------------------------------------------------------
DEVFN void ln_body(const float* __restrict__ x, const float* __restrict__ w,
                   const float* __restrict__ b, ushort_t* __restrict__ out,
                   int row) {
    const float4* xr4 = (const float4*)(x + (size_t)row * 1024);
    ushort_t* orow = out + (size_t)row * 1024;
    int tid = threadIdx.x;
    float4 v4 = xr4[tid];
    float s = v4.x + v4.y + v4.z + v4.w;
    float ss = v4.x * v4.x + v4.y * v4.y + v4.z * v4.z + v4.w * v4.w;
#pragma unroll
    for (int off = 32; off > 0; off >>= 1) {
        s += __shfl_down(s, off);
        ss += __shfl_down(ss, off);
    }
    __shared__ float red[8];
    if ((tid & 63) == 0) {
        red[tid >> 6] = s;
        red[4 + (tid >> 6)] = ss;
    }
    __syncthreads();
    s = red[0] + red[1] + red[2] + red[3];
    ss = red[4] + red[5] + red[6] + red[7];
    float mean = s * (1.f / 1024.f);
    float var = ss * (1.f / 1024.f) - mean * mean;
    float rstd = rsqrtf(var + 1e-5f);
    const float4 w4 = ((const float4*)w)[tid];
    const float4 b4 = ((const float4*)b)[tid];
    union { ushort_t u[4]; uint2 v; } pk;
    pk.u[0] = f2bf((v4.x - mean) * rstd * w4.x + b4.x);
    pk.u[1] = f2bf((v4.y - mean) * rstd * w4.y + b4.y);
    pk.u[2] = f2bf((v4.z - mean) * rstd * w4.z + b4.z);
    pk.u[3] = f2bf((v4.w - mean) * rstd * w4.w + b4.w);
    *(uint2*)(&orow[tid * 4]) = pk.v;
}

struct LNSeg {
    const float* x; const float* w; const float* b; ushort_t* out; int start;
};
struct TDesc { const float* in; ushort_t* out; int R, C, nx, start; };

// ---------------------------------------------------------------------------
// 64x64 transpose tile (fp32 [R,C] -> bf16 [C,R]), vectorized (round-9).
// ---------------------------------------------------------------------------
DEVFN void transpose_body(TDesc d, int t, ushort_t* lds) {
    int bx = (t % d.nx) * 64;
    int by = (t / d.nx) * 64;
    int tid = threadIdx.x;
#pragma unroll
    for (int it = 0; it < 4; it++) {
        int idx = it * 256 + tid;        // 0..1023
        int r = idx >> 4;                // 0..63
        int c4 = (idx & 15) << 2;        // 0,4,...,60
        float4 v = *(const float4*)(&d.in[(size_t)(by + r) * d.C + bx + c4]);
        float vals[4] = {v.x, v.y, v.z, v.w};
#pragma unroll
        for (int j = 0; j < 4; j++) {
            int c = c4 + j;
            int rs = (r + (((c >> 2) & 7) << 3)) & 63;
            lds[c * 64 + rs] = f2bf(vals[j]);
        }
    }
    __syncthreads();
#pragma unroll
    for (int it = 0; it < 2; it++) {
        int idx = it * 256 + tid;        // 0..511
        int c = idx >> 3;                // 0..63
        int l8 = idx & 7;
        int rs = ((l8 << 3) + (((c >> 2) & 7) << 3)) & 63;
        uint4 val = *(const uint4*)(&lds[c * 64 + rs]);
        *(uint4*)(&d.out[(size_t)(bx + c) * d.R + by + (l8 << 3)]) = val;
    }
    __syncthreads();  // safe LDS reuse by caller
}

// ---------------------------------------------------------------------------
// prep: blocks [0,896) = 3 LayerNorms; rest = Wq/Wkv transposes.
// ---------------------------------------------------------------------------
__global__ __launch_bounds__(256) void prep_kernel(LNSeg l0, LNSeg l1,
                                                   LNSeg l2, TDesc d0,
                                                   TDesc d1) {
    int id = blockIdx.x;
    if (id < 896) {
        LNSeg s = (id >= l2.start) ? l2 : ((id >= l1.start) ? l1 : l0);
        ln_body(s.x, s.w, s.b, s.out, id - s.start);
        return;
    }
    id -= 896;
    __shared__ ushort_t tile[64 * 64];
    TDesc d = (id >= d1.start) ? d1 : d0;
    transpose_body(d, id - d.start, tile);
}

// ---------------------------------------------------------------------------
// Pipelined MFMA bf16 GEMM core, BK=64: 64x64 tile, 256 threads (2x2 waves),
// LS=72. EPI: 0 = bf16 store; 4 = raw fp32 store (split-K partial);
// 5 = +bias +resid fp32 store AND per-row (sum,sum^2) partials -> stats.
// ---------------------------------------------------------------------------
template <int EPI, typename OutT>
DEVFN void gemm64_core(const ushort_t* __restrict__ A, int lda,
                       const ushort_t* __restrict__ B, int ldb,
                       OutT* __restrict__ C, int ldc,
                       const float* __restrict__ bias,
                       const float* __restrict__ resid, int K, int m0, int n0,
                       ushort_t* As, ushort_t* Bs,
                       float* __restrict__ stats = nullptr) {
    constexpr int LS = 72;
    int tid = threadIdx.x;
    int wave = tid >> 6, lane = tid & 63;
    int wm = wave >> 1, wn = wave & 1;
    int quad = lane >> 4, l16 = lane & 15;

    f32x4 acc[2][2];
#pragma unroll
    for (int i = 0; i < 2; i++)
#pragma unroll
        for (int j = 0; j < 2; j++) acc[i][j] = (f32x4){0.f, 0.f, 0.f, 0.f};

    int r = tid >> 3;  // 0..31
    int c = tid & 7;   // k-chunk of 8 bf16
    const ushort_t* Ap = A + (size_t)(m0 + r) * lda + c * 8;
    const ushort_t* Bp = B + (size_t)(n0 + r) * ldb + c * 8;
    const ushort_t* Ap2 = Ap + (size_t)32 * lda;
    const ushort_t* Bp2 = Bp + (size_t)32 * ldb;
    uint4 ra = *(const uint4*)Ap, ra2 = *(const uint4*)Ap2;
    uint4 rb = *(const uint4*)Bp, rb2 = *(const uint4*)Bp2;

    for (int k0 = 0; k0 < K; k0 += 64) {
        *(uint4*)(&As[r * LS + c * 8]) = ra;
        *(uint4*)(&As[(r + 32) * LS + c * 8]) = ra2;
        *(uint4*)(&Bs[r * LS + c * 8]) = rb;
        *(uint4*)(&Bs[(r + 32) * LS + c * 8]) = rb2;
        __syncthreads();
        if (k0 + 64 < K) {
            ra = *(const uint4*)(Ap + k0 + 64);
            ra2 = *(const uint4*)(Ap2 + k0 + 64);
            rb = *(const uint4*)(Bp + k0 + 64);
            rb2 = *(const uint4*)(Bp2 + k0 + 64);
        }
#pragma unroll
        for (int ks = 0; ks < 2; ks++) {
            bf16x8 af[2], bfr[2];
#pragma unroll
            for (int i = 0; i < 2; i++)
                af[i] = *(const bf16x8*)(
                    &As[(wm * 32 + i * 16 + l16) * LS + ks * 32 + quad * 8]);
#pragma unroll
            for (int j = 0; j < 2; j++)
                bfr[j] = *(const bf16x8*)(
                    &Bs[(wn * 32 + j * 16 + l16) * LS + ks * 32 + quad * 8]);
#pragma unroll
            for (int i = 0; i < 2; i++)
#pragma unroll
                for (int j = 0; j < 2; j++)
                    acc[i][j] = __builtin_amdgcn_mfma_f32_16x16x32_bf16(
                        af[i], bfr[j], acc[i][j], 0, 0, 0);
        }
        __syncthreads();
    }

    float srow[2][4] = {{0.f, 0.f, 0.f, 0.f}, {0.f, 0.f, 0.f, 0.f}};
    float ssrow[2][4] = {{0.f, 0.f, 0.f, 0.f}, {0.f, 0.f, 0.f, 0.f}};

#pragma unroll
    for (int i = 0; i < 2; i++)
#pragma unroll
        for (int j = 0; j < 2; j++) {
            int col = n0 + wn * 32 + j * 16 + l16;
            int rbase = m0 + wm * 32 + i * 16 + quad * 4;
            float bv = (EPI == 5) ? bias[col] : 0.f;
#pragma unroll
            for (int rr = 0; rr < 4; rr++) {
                int row = rbase + rr;
                float vv = acc[i][j][rr] + bv;
                if constexpr (EPI == 5) {
                    vv += resid[(size_t)row * ldc + col];
                    srow[i][rr] += vv;
                    ssrow[i][rr] += vv * vv;
                }
                if constexpr (sizeof(OutT) == 2)
                    C[(size_t)row * ldc + col] = (OutT)f2bf(vv);
                else
                    C[(size_t)row * ldc + col] = vv;
            }
        }

    if constexpr (EPI == 5) {
        // reduce over the 16 lanes (l16) per wave, combine 2 wn-waves in LDS
        float* ls = (float*)As;  // free after final K-loop barrier
#pragma unroll
        for (int i = 0; i < 2; i++)
#pragma unroll
            for (int rr = 0; rr < 4; rr++) {
                float s = srow[i][rr], ss = ssrow[i][rr];
#pragma unroll
                for (int m = 1; m < 16; m <<= 1) {
                    s += __shfl_xor(s, m);
                    ss += __shfl_xor(ss, m);
                }
                if (l16 == 0) {
                    int rl = wm * 32 + i * 16 + quad * 4 + rr;  // 0..63
                    ls[rl * 4 + wn * 2 + 0] = s;
                    ls[rl * 4 + wn * 2 + 1] = ss;
                }
            }
        __syncthreads();
        if (tid < 64) {
            float s = ls[tid * 4 + 0] + ls[tid * 4 + 2];
            float ss = ls[tid * 4 + 1] + ls[tid * 4 + 3];
            stats[(size_t)(m0 + tid) * 2 + 0] = s;
            stats[(size_t)(m0 + tid) * 2 + 1] = ss;
        }
    }
}

template <int EPI, typename OutT>
__global__ __launch_bounds__(256) void gemm64(
    const ushort_t* __restrict__ A, int lda, const ushort_t* __restrict__ Bt,
    int ldb, OutT* __restrict__ C, int ldc, const float* __restrict__ bias,
    const float* __restrict__ resid, int Kper, int sliceStride) {
    __shared__ ushort_t As[64 * 72];
    __shared__ ushort_t Bs[64 * 72];
    int z = blockIdx.z;
    gemm64_core<EPI, OutT>(A + (size_t)z * Kper, lda, Bt + (size_t)z * Kper,
                           ldb, C + (size_t)z * sliceStride, ldc, bias, resid,
                           Kper, blockIdx.y * 64, blockIdx.x * 64, As, Bs);
}

struct GSeg {
    const ushort_t* A; const ushort_t* B; ushort_t* C;
    int lda, ldb, ldc, nx, start;
};

// ---------------------------------------------------------------------------
// proj launch: blocks [0,80) = q/kv_v/kv_a projections; rest = Wproj/W1/W2
// transposes backfilling idle CUs.
// ---------------------------------------------------------------------------
__global__ __launch_bounds__(256) void projT_kernel(GSeg s0, GSeg s1, GSeg s2,
                                                    TDesc d0, TDesc d1,
                                                    TDesc d2, int K) {
    __shared__ ushort_t As[64 * 72];
    __shared__ ushort_t Bs[64 * 72];
    int id = blockIdx.x;
    if (id < 80) {
        GSeg s = (id >= s2.start) ? s2 : ((id >= s1.start) ? s1 : s0);
        int t = id - s.start;
        int n0 = (t % s.nx) * 64;
        int m0 = (t / s.nx) * 64;
        gemm64_core<0, ushort_t>(s.A, s.lda, s.B, s.ldb, s.C, s.ldc, nullptr,
                                 nullptr, K, m0, n0, As, Bs);
        return;
    }
    id -= 80;
    TDesc d = (id >= d2.start) ? d2 : ((id >= d1.start) ? d1 : d0);
    transpose_body(d, id - d.start, As);
}

// ---------------------------------------------------------------------------
// ygemm: y = attnout @ Wproj + bproj + xmm (fp32) + per-row stats partials.
// ---------------------------------------------------------------------------
__global__ __launch_bounds__(256) void ygemm_kernel(
    const ushort_t* __restrict__ A, const ushort_t* __restrict__ Bt,
    float* __restrict__ y, const float* __restrict__ bproj,
    const float* __restrict__ xmm, float* __restrict__ pstats) {
    __shared__ ushort_t As[64 * 72];
    __shared__ ushort_t Bs[64 * 72];
    gemm64_core<5, float>(A, 256, Bt, 256, y, 1024, bproj, xmm, 256,
                          blockIdx.y * 64, blockIdx.x * 64, As, Bs,
                          pstats + (size_t)blockIdx.x * 512 * 2);
}

// ---------------------------------------------------------------------------
// mlp1 with fused LN (BK=64/LS=72 core): g = gelu(LN(y) @ W1 + b1), bf16.
// LN stats from pstats (16 partials/row, deterministic sum) -> LDS
// meanv/rstdv pre-pass; A-staging normalizes fp32 y -> bf16 inline.
// ---------------------------------------------------------------------------
__global__ __launch_bounds__(256) void mlp1_kernel(
    const float* __restrict__ y, const float* __restrict__ pstats,
    const float* __restrict__ lnw, const float* __restrict__ lnb,
    const ushort_t* __restrict__ W1t, const float* __restrict__ b1,
    ushort_t* __restrict__ g) {
    constexpr int LS = 72;
    __shared__ ushort_t As[64 * LS];
    __shared__ ushort_t Bs[64 * LS];
    __shared__ float wls[1024], bls[1024];
    __shared__ float meanv[64], rstdv[64];
    int tid = threadIdx.x;
    int m0 = blockIdx.y * 64, n0 = blockIdx.x * 64;

    ((float4*)wls)[tid] = ((const float4*)lnw)[tid];
    ((float4*)bls)[tid] = ((const float4*)lnb)[tid];

    // stats pre-pass: 64 rows x 4 threads; each sums 4 of 16 block partials
    {
        int row = tid >> 2, q = tid & 3;
        float s = 0.f, ss = 0.f;
#pragma unroll
        for (int k = 0; k < 4; k++) {
            size_t o = ((size_t)(q * 4 + k) * 512 + (m0 + row)) * 2;
            s += pstats[o];
            ss += pstats[o + 1];
        }
        s += __shfl_xor(s, 1); ss += __shfl_xor(ss, 1);
        s += __shfl_xor(s, 2); ss += __shfl_xor(ss, 2);
        if (q == 0) {
            float mean = s * (1.f / 1024.f);
            float var = ss * (1.f / 1024.f) - mean * mean;
            meanv[row] = mean;
            rstdv[row] = rsqrtf(var + 1e-5f);
        }
    }

    int wave = tid >> 6, lane = tid & 63;
    int wm = wave >> 1, wn = wave & 1;
    int quad = lane >> 4, l16 = lane & 15;

    f32x4 acc[2][2];
#pragma unroll
    for (int i = 0; i < 2; i++)
#pragma unroll
        for (int j = 0; j < 2; j++) acc[i][j] = (f32x4){0.f, 0.f, 0.f, 0.f};

    int r = tid >> 3;  // 0..31
    int c = tid & 7;   // k-chunk of 8
    const float* Ay = y + (size_t)(m0 + r) * 1024 + c * 8;
    const float* Ay2 = Ay + (size_t)32 * 1024;
    const ushort_t* Bp = W1t + (size_t)(n0 + r) * 1024 + c * 8;
    const ushort_t* Bp2 = Bp + (size_t)32 * 1024;

    __syncthreads();  // wls/bls + meanv/rstdv ready
    float mr0 = meanv[r], rs0 = rstdv[r];
    float mr1 = meanv[r + 32], rs1 = rstdv[r + 32];

    float4 a00 = *(const float4*)(Ay);
    float4 a01 = *(const float4*)(Ay + 4);
    float4 a10 = *(const float4*)(Ay2);
    float4 a11 = *(const float4*)(Ay2 + 4);
    uint4 rb = *(const uint4*)Bp;
    uint4 rb2 = *(const uint4*)Bp2;

    for (int k0 = 0; k0 < 1024; k0 += 64) {
        float4 w0 = *(const float4*)&wls[k0 + c * 8];
        float4 w1 = *(const float4*)&wls[k0 + c * 8 + 4];
        float4 bb0 = *(const float4*)&bls[k0 + c * 8];
        float4 bb1 = *(const float4*)&bls[k0 + c * 8 + 4];
        union { ushort_t u[8]; uint4 v; } p0, p1;
        p0.u[0] = f2bf((a00.x - mr0) * rs0 * w0.x + bb0.x);
        p0.u[1] = f2bf((a00.y - mr0) * rs0 * w0.y + bb0.y);
        p0.u[2] = f2bf((a00.z - mr0) * rs0 * w0.z + bb0.z);
        p0.u[3] = f2bf((a00.w - mr0) * rs0 * w0.w + bb0.w);
        p0.u[4] = f2bf((a01.x - mr0) * rs0 * w1.x + bb1.x);
        p0.u[5] = f2bf((a01.y - mr0) * rs0 * w1.y + bb1.y);
        p0.u[6] = f2bf((a01.z - mr0) * rs0 * w1.z + bb1.z);
        p0.u[7] = f2bf((a01.w - mr0) * rs0 * w1.w + bb1.w);
        p1.u[0] = f2bf((a10.x - mr1) * rs1 * w0.x + bb0.x);
        p1.u[1] = f2bf((a10.y - mr1) * rs1 * w0.y + bb0.y);
        p1.u[2] = f2bf((a10.z - mr1) * rs1 * w0.z + bb0.z);
        p1.u[3] = f2bf((a10.w - mr1) * rs1 * w0.w + bb0.w);
        p1.u[4] = f2bf((a11.x - mr1) * rs1 * w1.x + bb1.x);
        p1.u[5] = f2bf((a11.y - mr1) * rs1 * w1.y + bb1.y);
        p1.u[6] = f2bf((a11.z - mr1) * rs1 * w1.z + bb1.z);
        p1.u[7] = f2bf((a11.w - mr1) * rs1 * w1.w + bb1.w);
        *(uint4*)(&As[r * LS + c * 8]) = p0.v;
        *(uint4*)(&As[(r + 32) * LS + c * 8]) = p1.v;
        *(uint4*)(&Bs[r * LS + c * 8]) = rb;
        *(uint4*)(&Bs[(r + 32) * LS + c * 8]) = rb2;
        __syncthreads();
        if (k0 + 64 < 1024) {
            a00 = *(const float4*)(Ay + k0 + 64);
            a01 = *(const float4*)(Ay + k0 + 68);
            a10 = *(const float4*)(Ay2 + k0 + 64);
            a11 = *(const float4*)(Ay2 + k0 + 68);
            rb = *(const uint4*)(Bp + k0 + 64);
            rb2 = *(const uint4*)(Bp2 + k0 + 64);
        }
#pragma unroll
        for (int ks = 0; ks < 2; ks++) {
            bf16x8 af[2], bfr[2];
#pragma unroll
            for (int i = 0; i < 2; i++)
                af[i] = *(const bf16x8*)(
                    &As[(wm * 32 + i * 16 + l16) * LS + ks * 32 + quad * 8]);
#pragma unroll
            for (int j = 0; j < 2; j++)
                bfr[j] = *(const bf16x8*)(
                    &Bs[(wn * 32 + j * 16 + l16) * LS + ks * 32 + quad * 8]);
#pragma unroll
            for (int i = 0; i < 2; i++)
#pragma unroll
                for (int j = 0; j < 2; j++)
                    acc[i][j] = __builtin_amdgcn_mfma_f32_16x16x32_bf16(
                        af[i], bfr[j], acc[i][j], 0, 0, 0);
        }
        __syncthreads();
    }

    // epilogue: +b1, exact GELU, bf16 store (ldc = 4096)
#pragma unroll
    for (int i = 0; i < 2; i++)
#pragma unroll
        for (int j = 0; j < 2; j++) {
            int col = n0 + wn * 32 + j * 16 + l16;
            int rbase = m0 + wm * 32 + i * 16 + quad * 4;
            float bv = b1[col];
#pragma unroll
            for (int rr = 0; rr < 4; rr++) {
                int row = rbase + rr;
                float vv = acc[i][j][rr] + bv;
                vv = 0.5f * vv * (1.f + erff(vv * 0.70710678118654752f));
                g[(size_t)row * 4096 + col] = f2bf(vv);
            }
        }
}

// ---------------------------------------------------------------------------
// mlp2 split-K reduce: out = sum_z P[z] + b2 + y  (round-9 verbatim)
// ---------------------------------------------------------------------------
__global__ __launch_bounds__(256) void reduce_mlp2(
    const float* __restrict__ P, const float* __restrict__ y,
    const float* __restrict__ b2, float* __restrict__ out) {
    int i = blockIdx.x * 256 + threadIdx.x;
    const float4* p = (const float4*)P;
    float4 a = p[i], b = p[i + 131072], cc = p[i + 2 * 131072],
           d = p[i + 3 * 131072];
    float4 yy = ((const float4*)y)[i];
    float4 bb = ((const float4*)b2)[i & 255];
    float4 o;
    o.x = a.x + b.x + cc.x + d.x + yy.x + bb.x;
    o.y = a.y + b.y + cc.y + d.y + yy.y + bb.y;
    o.z = a.z + b.z + cc.z + d.z + yy.z + bb.z;
    o.w = a.w + b.w + cc.w + d.w + yy.w + bb.w;
    ((float4*)out)[i] = o;
}

// ---------------------------------------------------------------------------
// Factorized attention (round-4 layout, verified).
// ---------------------------------------------------------------------------
__global__ __launch_bounds__(256) void attn_kernel(
    const ushort_t* __restrict__ q, const ushort_t* __restrict__ kvv,
    const ushort_t* __restrict__ kva, ushort_t* __restrict__ out) {
    int bh = blockIdx.x;
    int b = bh >> 4, h = bh & 15;
    int tid = threadIdx.x;

    __shared__ float Kv[64][16], Vv[64][16], Ka[128][16], Va[128][16];

    {
        int row = tid >> 2, seg = (tid >> 1) & 1, half = tid & 1;
        const ushort_t* src =
            kvv + (size_t)(b * 64 + row) * 512 + seg * 256 + h * 16 + half * 8;
        float* dst = (seg ? Vv[row] : Kv[row]) + half * 8;
        unpack8(*(const uint4*)src, dst);
    }
#pragma unroll
    for (int t2 = 0; t2 < 2; t2++) {
        int t = tid + t2 * 256;
        int row = t >> 2, seg = (t >> 1) & 1, half = t & 1;
        const ushort_t* src =
            kva + (size_t)(b * 128 + row) * 512 + seg * 256 + h * 16 + half * 8;
        float* dst = (seg ? Va[row] : Ka[row]) + half * 8;
        unpack8(*(const uint4*)src, dst);
    }
    __syncthreads();

    int qlocal = tid >> 2;  // 0..63
    int dg = tid & 3;
    int qrow = blockIdx.y * 64 + qlocal;
    const ushort_t* qp = q + (size_t)(b * 256 + qrow) * 256 + h * 16 + dg * 4;
    uint2 qu = *(const uint2*)qp;
    float4 qv;
    qv.x = __uint_as_float(qu.x << 16) * 0.125f;
    qv.y = __uint_as_float(qu.x & 0xFFFF0000u) * 0.125f;
    qv.z = __uint_as_float(qu.y << 16) * 0.125f;
    qv.w = __uint_as_float(qu.y & 0xFFFF0000u) * 0.125f;

    const float4* Kv4 = (const float4*)Kv;
    const float4* Vv4 = (const float4*)Vv;
    const float4* Ka4 = (const float4*)Ka;
    const float4* Va4 = (const float4*)Va;

    float4 ov = {0.f, 0.f, 0.f, 0.f};
    float den = 0.f;
#pragma unroll 8
    for (int i = 0; i < 64; i++) {
        float4 kk = Kv4[i * 4 + dg];
        float part = qv.x * kk.x + qv.y * kk.y + qv.z * kk.z + qv.w * kk.w;
        part += __shfl_xor(part, 1);
        part += __shfl_xor(part, 2);
        float p = __expf(part);
        den += p;
        float4 vv = Vv4[i * 4 + dg];
        ov.x += p * vv.x; ov.y += p * vv.y; ov.z += p * vv.z; ov.w += p * vv.w;
    }
    float4 oa = {0.f, 0.f, 0.f, 0.f};
    float dena = 0.f;
#pragma unroll 8
    for (int i = 0; i < 128; i++) {
        float4 kk = Ka4[i * 4 + dg];
        float part = qv.x * kk.x + qv.y * kk.y + qv.z * kk.z + qv.w * kk.w;
        part += __shfl_xor(part, 1);
        part += __shfl_xor(part, 2);
        float p = __expf(part);
        dena += p;
        float4 vv = Va4[i * 4 + dg];
        oa.x += p * vv.x; oa.y += p * vv.y; oa.z += p * vv.z; oa.w += p * vv.w;
    }

    float rv = 1.f / den, ra = 1.f / dena;
    union { ushort_t u[4]; uint2 v; } pk;
    pk.u[0] = f2bf(ov.x * rv + oa.x * ra);
    pk.u[1] = f2bf(ov.y * rv + oa.y * ra);
    pk.u[2] = f2bf(ov.z * rv + oa.z * ra);
    pk.u[3] = f2bf(ov.w * rv + oa.w * ra);
    *(uint2*)(out + (size_t)(b * 256 + qrow) * 256 + h * 16 + dg * 4) = pk.v;
}

// ---------------------------------------------------------------------------
extern "C" void kernel_launch(void* const* d_in, const int* in_sizes, int n_in,
                              void* d_out, int out_size, void* d_ws,
                              size_t ws_size, hipStream_t stream) {
    const float* xmm = (const float*)d_in[0];
    const float* xv = (const float*)d_in[1];
    const float* xa = (const float*)d_in[2];
    const float* ln_mm_w = (const float*)d_in[3];
    const float* ln_mm_b = (const float*)d_in[4];
    const float* ln_v_w = (const float*)d_in[5];
    const float* ln_v_b = (const float*)d_in[6];
    const float* ln_a_w = (const float*)d_in[7];
    const float* ln_a_b = (const float*)d_in[8];
    const float* Wq = (const float*)d_in[9];
    const float* Wkv = (const float*)d_in[10];
    const float* Wproj = (const float*)d_in[11];
    const float* bproj = (const float*)d_in[12];
    const float* ln_mlp_w = (const float*)d_in[13];
    const float* ln_mlp_b = (const float*)d_in[14];
    const float* W1 = (const float*)d_in[15];
    const float* b1 = (const float*)d_in[16];
    const float* W2 = (const float*)d_in[17];
    const float* b2 = (const float*)d_in[18];
    float* outp = (float*)d_out;

    char* w = (char*)d_ws;
    float* pstats = (float*)w;        w += 16 * 512 * 2 * 4;   // 64 KB
    ushort_t* xmmN = (ushort_t*)w;    w += 512 * 1024 * 2;
    ushort_t* xvN = (ushort_t*)w;     w += 128 * 1024 * 2;
    ushort_t* xaN = (ushort_t*)w;     w += 256 * 1024 * 2;
    ushort_t* Wqt = (ushort_t*)w;     w += 256 * 1024 * 2;
    ushort_t* Wkvt = (ushort_t*)w;    w += 512 * 2048 * 2;
    ushort_t* Wprojt = (ushort_t*)w;  w += 1024 * 256 * 2;
    ushort_t* W1t = (ushort_t*)w;     w += 4096 * 1024 * 2;
    ushort_t* W2t = (ushort_t*)w;     w += 1024 * 4096 * 2;
    ushort_t* qout = (ushort_t*)w;    w += 512 * 256 * 2;
    ushort_t* kvvb = (ushort_t*)w;    w += 128 * 512 * 2;
    ushort_t* kvab = (ushort_t*)w;    w += 256 * 512 * 2;
    ushort_t* attnout = (ushort_t*)w; w += 512 * 256 * 2;
    float* y = (float*)w;             w += 512 * 1024 * 4;
    ushort_t* g = (ushort_t*)w;       w += 512 * 4096 * 2;
    float* P = (float*)w;             w += 4 * 512 * 1024 * 4;

    // 1) prep: 3 LayerNorms + Wq/Wkv transposes (64+256 tiles of 64x64)
    LNSeg L0{xmm, ln_mm_w, ln_mm_b, xmmN, 0};
    LNSeg L1{xv, ln_v_w, ln_v_b, xvN, 512};
    LNSeg L2{xa, ln_a_w, ln_a_b, xaN, 640};
    TDesc TQ{Wq, Wqt, 1024, 256, 4, 0};       // 64 tiles
    TDesc TKV{Wkv, Wkvt, 2048, 512, 8, 64};   // 256 tiles
    prep_kernel<<<896 + 320, 256, 0, stream>>>(L0, L1, L2, TQ, TKV);

    // 2) projections (80) + Wproj/W1/W2 transposes (2112)
    GSeg G0{xmmN, Wqt, qout, 1024, 1024, 256, 4, 0};
    GSeg G1{xvN, Wkvt, kvvb, 1024, 2048, 512, 8, 32};
    GSeg G2{xaN, Wkvt + 1024, kvab, 1024, 2048, 512, 8, 48};
    TDesc TP{Wproj, Wprojt, 256, 1024, 16, 0};    // 64 tiles
    TDesc T1{W1, W1t, 1024, 4096, 64, 64};        // 1024 tiles
    TDesc T2{W2, W2t, 4096, 1024, 16, 1088};      // 1024 tiles
    projT_kernel<<<80 + 2112, 256, 0, stream>>>(G0, G1, G2, TP, T1, T2, 1024);

    // 3) factorized attention
    attn_kernel<<<dim3(32, 4), 256, 0, stream>>>(qout, kvvb, kvab, attnout);

    // 4) y = attnout @ Wproj + bproj + xmm (fp32) + LN stats partials
    ygemm_kernel<<<dim3(16, 8), 256, 0, stream>>>(attnout, Wprojt, y, bproj,
                                                  xmm, pstats);

    // 5) g = gelu(LN(y) @ W1 + b1)  (LN fused via pstats, BK=64 core)
    mlp1_kernel<<<dim3(64, 8), 256, 0, stream>>>(y, pstats, ln_mlp_w,
                                                 ln_mlp_b, W1t, b1, g);

    // 6) split-K=4: P[z] = g @ W2 (k-slice z)  [4][512,1024] fp32
    gemm64<4, float><<<dim3(16, 8, 4), 256, 0, stream>>>(
        g, 4096, W2t, 4096, P, 1024, nullptr, nullptr, 1024, 512 * 1024);

    // 7) out = sum P + b2 + y
    reduce_mlp2<<<512, 256, 0, stream>>>(P, y, b2, outp);

    (void)in_sizes; (void)n_in; (void)out_size; (void)ws_size;
}

// Round 9
// 182.945 us; speedup vs baseline: 2.8011x; 1.0338x over previous
//
#include <hip/hip_runtime.h>
#include <hip/hip_bf16.h>
#include <math.h>

// ---------------------------------------------------------------------------
// FusionBlock_DenseAVInteractions — round 13
//
// Round-12 post-mortem: fused-LN mlp1 (BK=64) regressed +5 us — the inline
// normalize sits on the staging critical path and is recomputed per n-block.
// Pattern now confirmed 3x: inter-kernel fusion loses on this problem;
// intra-kernel wins (BK=64, vectorized transpose, backfill) are the lever.
//
// Round-13 = round-9 (184.2 verified) + two intra-kernel changes:
//  * all GEMM cores: double-buffered LDS -> ONE barrier per K-step
//    (write next tile to the idle buffer; 16 of 32 barriers removed at
//    K=1024; accumulation order unchanged -> bitwise-identical).
//  * transpose re-placement: W1-transpose moves into the attn launch
//    (128 attn blocks leave ~220 CUs idle), W2-transpose into the mlp1
//    launch (MFMA-heavy cover). projT keeps proj GEMM + Wproj only.
//    Dependency chain: W1t ready before mlp1 (launch 5), W2t before mlp2
//    (launch 6) — ordering guaranteed by stream serialization.
// ---------------------------------------------------------------------------

typedef unsigned short ushort_t;
typedef __attribute__((ext_vector_type(8))) __bf16 bf16x8;
typedef __attribute__((ext_vector_type(4))) float f32x4;

#define DEVFN static __device__ __forceinline__

DEVFN ushort_t f2bf(float f) {
    unsigned int x = __float_as_uint(f);
    unsigned int r = x + 0x7FFFu + ((x >> 16) & 1u);  // RNE
    return (ushort_t)(r >> 16);
}
// unpack 8 bf16 (uint4) -> 8 floats
DEVFN void unpack8(uint4 dv, float* dst) {
    unsigned int ws[4] = {dv.x, dv.y, dv.z, dv.w};
#pragma unroll
    for (int i = 0; i < 4; i++) {
        dst[2 * i] = __uint_as_float(ws[i] << 16);
        dst[2 * i + 1] = __uint_as_float(ws[i] & 0xFFFF0000u);
    }
}

// ---------------------------------------------------------------------------
// LayerNorm body: one 256-thread block per row of 1024. fp32 in -> bf16 out.
// ---------------------------------------------------------------------------
DEVFN void ln_body(const float* __restrict__ x, const float* __restrict__ w,
                   const float* __restrict__ b, ushort_t* __restrict__ out,
                   int row) {
    const float4* xr4 = (const float4*)(x + (size_t)row * 1024);
    ushort_t* orow = out + (size_t)row * 1024;
    int tid = threadIdx.x;
    float4 v4 = xr4[tid];
    float s = v4.x + v4.y + v4.z + v4.w;
    float ss = v4.x * v4.x + v4.y * v4.y + v4.z * v4.z + v4.w * v4.w;
#pragma unroll
    for (int off = 32; off > 0; off >>= 1) {
        s += __shfl_down(s, off);
        ss += __shfl_down(ss, off);
    }
    __shared__ float red[8];
    if ((tid & 63) == 0) {
        red[tid >> 6] = s;
        red[4 + (tid >> 6)] = ss;
    }
    __syncthreads();
    s = red[0] + red[1] + red[2] + red[3];
    ss = red[4] + red[5] + red[6] + red[7];
    float mean = s * (1.f / 1024.f);
    float var = ss * (1.f / 1024.f) - mean * mean;
    float rstd = rsqrtf(var + 1e-5f);
    const float4 w4 = ((const float4*)w)[tid];
    const float4 b4 = ((const float4*)b)[tid];
    union { ushort_t u[4]; uint2 v; } pk;
    pk.u[0] = f2bf((v4.x - mean) * rstd * w4.x + b4.x);
    pk.u[1] = f2bf((v4.y - mean) * rstd * w4.y + b4.y);
    pk.u[2] = f2bf((v4.z - mean) * rstd * w4.z + b4.z);
    pk.u[3] = f2bf((v4.w - mean) * rstd * w4.w + b4.w);
    *(uint2*)(&orow[tid * 4]) = pk.v;
}

__global__ __launch_bounds__(256) void ln_kernel(
    const float* __restrict__ x, const float* __restrict__ w,
    const float* __restrict__ b, ushort_t* __restrict__ out) {
    ln_body(x, w, b, out, blockIdx.x);
}

struct LNSeg {
    const float* x; const float* w; const float* b; ushort_t* out; int start;
};
struct TDesc { const float* in; ushort_t* out; int R, C, nx, start; };

// ---------------------------------------------------------------------------
// 64x64 transpose tile (fp32 [R,C] -> bf16 [C,R]), vectorized (round-9).
// ---------------------------------------------------------------------------
DEVFN void transpose_body(TDesc d, int t, ushort_t* lds) {
    int bx = (t % d.nx) * 64;
    int by = (t / d.nx) * 64;
    int tid = threadIdx.x;
#pragma unroll
    for (int it = 0; it < 4; it++) {
        int idx = it * 256 + tid;        // 0..1023
        int r = idx >> 4;                // 0..63
        int c4 = (idx & 15) << 2;        // 0,4,...,60
        float4 v = *(const float4*)(&d.in[(size_t)(by + r) * d.C + bx + c4]);
        float vals[4] = {v.x, v.y, v.z, v.w};
#pragma unroll
        for (int j = 0; j < 4; j++) {
            int c = c4 + j;
            int rs = (r + (((c >> 2) & 7) << 3)) & 63;
            lds[c * 64 + rs] = f2bf(vals[j]);
        }
    }
    __syncthreads();
#pragma unroll
    for (int it = 0; it < 2; it++) {
        int idx = it * 256 + tid;        // 0..511
        int c = idx >> 3;                // 0..63
        int l8 = idx & 7;
        int rs = ((l8 << 3) + (((c >> 2) & 7) << 3)) & 63;
        uint4 val = *(const uint4*)(&lds[c * 64 + rs]);
        *(uint4*)(&d.out[(size_t)(bx + c) * d.R + by + (l8 << 3)]) = val;
    }
    __syncthreads();  // safe LDS reuse by caller
}

// ---------------------------------------------------------------------------
// prep: blocks [0,896) = 3 LayerNorms; rest = Wq/Wkv transposes.
// ---------------------------------------------------------------------------
__global__ __launch_bounds__(256) void prep_kernel(LNSeg l0, LNSeg l1,
                                                   LNSeg l2, TDesc d0,
                                                   TDesc d1) {
    int id = blockIdx.x;
    if (id < 896) {
        LNSeg s = (id >= l2.start) ? l2 : ((id >= l1.start) ? l1 : l0);
        ln_body(s.x, s.w, s.b, s.out, id - s.start);
        return;
    }
    id -= 896;
    __shared__ ushort_t tile[64 * 64];
    TDesc d = (id >= d1.start) ? d1 : d0;
    transpose_body(d, id - d.start, tile);
}

// ---------------------------------------------------------------------------
// Pipelined MFMA bf16 GEMM core, BK=64, DOUBLE-BUFFERED LDS: one barrier per
// K-step (write tile t+1 to the idle buffer while MFMAs read the other).
// 64x64 tile, 256 threads (2x2 waves), LS=72. Accumulation order unchanged.
// As/Bs each point to 2 x 64*72 ushort buffers (18432 B each).
// EPI: 0 = bf16 store; 2 = +bias +exact GELU, bf16; 3 = +bias +resid, fp32;
//      4 = raw fp32 store (split-K partial)
// ---------------------------------------------------------------------------
template <int EPI, typename OutT>
DEVFN void gemm64_core(const ushort_t* __restrict__ A, int lda,
                       const ushort_t* __restrict__ B, int ldb,
                       OutT* __restrict__ C, int ldc,
                       const float* __restrict__ bias,
                       const float* __restrict__ resid, int K, int m0, int n0,
                       ushort_t* As, ushort_t* Bs) {
    constexpr int LS = 72;
    constexpr int BUF = 64 * LS;  // 4608 ushorts per buffer
    int tid = threadIdx.x;
    int wave = tid >> 6, lane = tid & 63;
    int wm = wave >> 1, wn = wave & 1;
    int quad = lane >> 4, l16 = lane & 15;

    f32x4 acc[2][2];
#pragma unroll
    for (int i = 0; i < 2; i++)
#pragma unroll
        for (int j = 0; j < 2; j++) acc[i][j] = (f32x4){0.f, 0.f, 0.f, 0.f};

    int r = tid >> 3;  // 0..31
    int c = tid & 7;   // k-chunk of 8 bf16
    const ushort_t* Ap = A + (size_t)(m0 + r) * lda + c * 8;
    const ushort_t* Bp = B + (size_t)(n0 + r) * ldb + c * 8;
    const ushort_t* Ap2 = Ap + (size_t)32 * lda;
    const ushort_t* Bp2 = Bp + (size_t)32 * ldb;
    uint4 ra = *(const uint4*)Ap, ra2 = *(const uint4*)Ap2;
    uint4 rb = *(const uint4*)Bp, rb2 = *(const uint4*)Bp2;

    int p = 0;
    for (int k0 = 0; k0 < K; k0 += 64) {
        ushort_t* Ab = As + p * BUF;
        ushort_t* Bb = Bs + p * BUF;
        *(uint4*)(&Ab[r * LS + c * 8]) = ra;
        *(uint4*)(&Ab[(r + 32) * LS + c * 8]) = ra2;
        *(uint4*)(&Bb[r * LS + c * 8]) = rb;
        *(uint4*)(&Bb[(r + 32) * LS + c * 8]) = rb2;
        __syncthreads();  // single barrier: buffer p ready for all waves
        if (k0 + 64 < K) {
            ra = *(const uint4*)(Ap + k0 + 64);
            ra2 = *(const uint4*)(Ap2 + k0 + 64);
            rb = *(const uint4*)(Bp + k0 + 64);
            rb2 = *(const uint4*)(Bp2 + k0 + 64);
        }
#pragma unroll
        for (int ks = 0; ks < 2; ks++) {
            bf16x8 af[2], bfr[2];
#pragma unroll
            for (int i = 0; i < 2; i++)
                af[i] = *(const bf16x8*)(
                    &Ab[(wm * 32 + i * 16 + l16) * LS + ks * 32 + quad * 8]);
#pragma unroll
            for (int j = 0; j < 2; j++)
                bfr[j] = *(const bf16x8*)(
                    &Bb[(wn * 32 + j * 16 + l16) * LS + ks * 32 + quad * 8]);
#pragma unroll
            for (int i = 0; i < 2; i++)
#pragma unroll
                for (int j = 0; j < 2; j++)
                    acc[i][j] = __builtin_amdgcn_mfma_f32_16x16x32_bf16(
                        af[i], bfr[j], acc[i][j], 0, 0, 0);
        }
        p ^= 1;  // next tile goes to the buffer no wave is reading this step
    }

#pragma unroll
    for (int i = 0; i < 2; i++)
#pragma unroll
        for (int j = 0; j < 2; j++) {
            int col = n0 + wn * 32 + j * 16 + l16;
            int rbase = m0 + wm * 32 + i * 16 + quad * 4;
            float bv = (EPI == 2 || EPI == 3) ? bias[col] : 0.f;
#pragma unroll
            for (int rr = 0; rr < 4; rr++) {
                int row = rbase + rr;
                float vv = acc[i][j][rr] + bv;
                if (EPI == 2) vv = 0.5f * vv * (1.f + erff(vv * 0.70710678118654752f));
                if (EPI == 3) vv += resid[(size_t)row * ldc + col];
                if constexpr (sizeof(OutT) == 2)
                    C[(size_t)row * ldc + col] = (OutT)f2bf(vv);
                else
                    C[(size_t)row * ldc + col] = vv;
            }
        }
}

template <int EPI, typename OutT>
__global__ __launch_bounds__(256) void gemm64(
    const ushort_t* __restrict__ A, int lda, const ushort_t* __restrict__ Bt,
    int ldb, OutT* __restrict__ C, int ldc, const float* __restrict__ bias,
    const float* __restrict__ resid, int Kper, int sliceStride) {
    __shared__ ushort_t As[2 * 64 * 72];
    __shared__ ushort_t Bs[2 * 64 * 72];
    int z = blockIdx.z;
    gemm64_core<EPI, OutT>(A + (size_t)z * Kper, lda, Bt + (size_t)z * Kper,
                           ldb, C + (size_t)z * sliceStride, ldc, bias, resid,
                           Kper, blockIdx.y * 64, blockIdx.x * 64, As, Bs);
}

struct GSeg {
    const ushort_t* A; const ushort_t* B; ushort_t* C;
    int lda, ldb, ldc, nx, start;
};

// ---------------------------------------------------------------------------
// proj launch: blocks [0,80) = q/kv_v/kv_a projections; [80,144) = Wproj
// transpose (needed by ygemm, 2 launches later).
// ---------------------------------------------------------------------------
__global__ __launch_bounds__(256) void projT_kernel(GSeg s0, GSeg s1, GSeg s2,
                                                    TDesc dP, int K) {
    __shared__ ushort_t As[2 * 64 * 72];
    __shared__ ushort_t Bs[2 * 64 * 72];
    int id = blockIdx.x;
    if (id < 80) {
        GSeg s = (id >= s2.start) ? s2 : ((id >= s1.start) ? s1 : s0);
        int t = id - s.start;
        int n0 = (t % s.nx) * 64;
        int m0 = (t / s.nx) * 64;
        gemm64_core<0, ushort_t>(s.A, s.lda, s.B, s.ldb, s.C, s.ldc, nullptr,
                                 nullptr, K, m0, n0, As, Bs);
        return;
    }
    transpose_body(dP, id - 80, As);
}

// ---------------------------------------------------------------------------
// Factorized attention body (round-4 layout, verified); LDS passed in.
// ---------------------------------------------------------------------------
DEVFN void attn_body(const ushort_t* __restrict__ q,
                     const ushort_t* __restrict__ kvv,
                     const ushort_t* __restrict__ kva,
                     ushort_t* __restrict__ out, int bh, int qc, float* sm) {
    int b = bh >> 4, h = bh & 15;
    int tid = threadIdx.x;
    float (*Kv)[16] = (float(*)[16])sm;
    float (*Vv)[16] = (float(*)[16])(sm + 64 * 16);
    float (*Ka)[16] = (float(*)[16])(sm + 2 * 64 * 16);
    float (*Va)[16] = (float(*)[16])(sm + 2 * 64 * 16 + 128 * 16);

    {
        int row = tid >> 2, seg = (tid >> 1) & 1, half = tid & 1;
        const ushort_t* src =
            kvv + (size_t)(b * 64 + row) * 512 + seg * 256 + h * 16 + half * 8;
        float* dst = (seg ? Vv[row] : Kv[row]) + half * 8;
        unpack8(*(const uint4*)src, dst);
    }
#pragma unroll
    for (int t2 = 0; t2 < 2; t2++) {
        int t = tid + t2 * 256;
        int row = t >> 2, seg = (t >> 1) & 1, half = t & 1;
        const ushort_t* src =
            kva + (size_t)(b * 128 + row) * 512 + seg * 256 + h * 16 + half * 8;
        float* dst = (seg ? Va[row] : Ka[row]) + half * 8;
        unpack8(*(const uint4*)src, dst);
    }
    __syncthreads();

    int qlocal = tid >> 2;  // 0..63
    int dg = tid & 3;
    int qrow = qc * 64 + qlocal;
    const ushort_t* qp = q + (size_t)(b * 256 + qrow) * 256 + h * 16 + dg * 4;
    uint2 qu = *(const uint2*)qp;
    float4 qv;
    qv.x = __uint_as_float(qu.x << 16) * 0.125f;
    qv.y = __uint_as_float(qu.x & 0xFFFF0000u) * 0.125f;
    qv.z = __uint_as_float(qu.y << 16) * 0.125f;
    qv.w = __uint_as_float(qu.y & 0xFFFF0000u) * 0.125f;

    const float4* Kv4 = (const float4*)Kv;
    const float4* Vv4 = (const float4*)Vv;
    const float4* Ka4 = (const float4*)Ka;
    const float4* Va4 = (const float4*)Va;

    float4 ov = {0.f, 0.f, 0.f, 0.f};
    float den = 0.f;
#pragma unroll 8
    for (int i = 0; i < 64; i++) {
        float4 kk = Kv4[i * 4 + dg];
        float part = qv.x * kk.x + qv.y * kk.y + qv.z * kk.z + qv.w * kk.w;
        part += __shfl_xor(part, 1);
        part += __shfl_xor(part, 2);
        float p = __expf(part);
        den += p;
        float4 vv = Vv4[i * 4 + dg];
        ov.x += p * vv.x; ov.y += p * vv.y; ov.z += p * vv.z; ov.w += p * vv.w;
    }
    float4 oa = {0.f, 0.f, 0.f, 0.f};
    float dena = 0.f;
#pragma unroll 8
    for (int i = 0; i < 128; i++) {
        float4 kk = Ka4[i * 4 + dg];
        float part = qv.x * kk.x + qv.y * kk.y + qv.z * kk.z + qv.w * kk.w;
        part += __shfl_xor(part, 1);
        part += __shfl_xor(part, 2);
        float p = __expf(part);
        dena += p;
        float4 vv = Va4[i * 4 + dg];
        oa.x += p * vv.x; oa.y += p * vv.y; oa.z += p * vv.z; oa.w += p * vv.w;
    }

    float rv = 1.f / den, ra = 1.f / dena;
    union { ushort_t u[4]; uint2 v; } pk;
    pk.u[0] = f2bf(ov.x * rv + oa.x * ra);
    pk.u[1] = f2bf(ov.y * rv + oa.y * ra);
    pk.u[2] = f2bf(ov.z * rv + oa.z * ra);
    pk.u[3] = f2bf(ov.w * rv + oa.w * ra);
    *(uint2*)(out + (size_t)(b * 256 + qrow) * 256 + h * 16 + dg * 4) = pk.v;
}

// ---------------------------------------------------------------------------
// attn launch: blocks [0,128) = attention; [128, 128+1024) = W1 transpose
// (needed by mlp1, 2 launches later) backfilling idle CUs.
// ---------------------------------------------------------------------------
__global__ __launch_bounds__(256) void attnT_kernel(
    const ushort_t* __restrict__ q, const ushort_t* __restrict__ kvv,
    const ushort_t* __restrict__ kva, ushort_t* __restrict__ out, TDesc d1) {
    __shared__ __align__(16) char smem[24576];
    int id = blockIdx.x;
    if (id < 128) {
        attn_body(q, kvv, kva, out, id & 31, id >> 5, (float*)smem);
        return;
    }
    transpose_body(d1, id - 128, (ushort_t*)smem);
}

// ---------------------------------------------------------------------------
// mlp1 launch: blocks [0,512) = g = gelu(h0 @ W1 + b1); [512, 512+1024) =
// W2 transpose (needed by mlp2, next launch) under the MFMA-heavy cover.
// ---------------------------------------------------------------------------
__global__ __launch_bounds__(256) void mlp1T_kernel(
    const ushort_t* __restrict__ h0, const ushort_t* __restrict__ W1t,
    const float* __restrict__ b1, ushort_t* __restrict__ g, TDesc d2) {
    __shared__ ushort_t As[2 * 64 * 72];
    __shared__ ushort_t Bs[2 * 64 * 72];
    int id = blockIdx.x;
    if (id < 512) {
        int n0 = (id % 64) * 64, m0 = (id / 64) * 64;
        gemm64_core<2, ushort_t>(h0, 1024, W1t, 1024, g, 4096, b1, nullptr,
                                 1024, m0, n0, As, Bs);
        return;
    }
    transpose_body(d2, id - 512, As);
}

// ---------------------------------------------------------------------------
// mlp2 split-K reduce: out = sum_z P[z] + b2 + y
// ---------------------------------------------------------------------------
__global__ __launch_bounds__(256) void reduce_mlp2(
    const float* __restrict__ P, const float* __restrict__ y,
    const float* __restrict__ b2, float* __restrict__ out) {
    int i = blockIdx.x * 256 + threadIdx.x;
    const float4* p = (const float4*)P;
    float4 a = p[i], b = p[i + 131072], cc = p[i + 2 * 131072],
           d = p[i + 3 * 131072];
    float4 yy = ((const float4*)y)[i];
    float4 bb = ((const float4*)b2)[i & 255];
    float4 o;
    o.x = a.x + b.x + cc.x + d.x + yy.x + bb.x;
    o.y = a.y + b.y + cc.y + d.y + yy.y + bb.y;
    o.z = a.z + b.z + cc.z + d.z + yy.z + bb.z;
    o.w = a.w + b.w + cc.w + d.w + yy.w + bb.w;
    ((float4*)out)[i] = o;
}

// ---------------------------------------------------------------------------
extern "C" void kernel_launch(void* const* d_in, const int* in_sizes, int n_in,
                              void* d_out, int out_size, void* d_ws,
                              size_t ws_size, hipStream_t stream) {
    const float* xmm = (const float*)d_in[0];
    const float* xv = (const float*)d_in[1];
    const float* xa = (const float*)d_in[2];
    const float* ln_mm_w = (const float*)d_in[3];
    const float* ln_mm_b = (const float*)d_in[4];
    const float* ln_v_w = (const float*)d_in[5];
    const float* ln_v_b = (const float*)d_in[6];
    const float* ln_a_w = (const float*)d_in[7];
    const float* ln_a_b = (const float*)d_in[8];
    const float* Wq = (const float*)d_in[9];
    const float* Wkv = (const float*)d_in[10];
    const float* Wproj = (const float*)d_in[11];
    const float* bproj = (const float*)d_in[12];
    const float* ln_mlp_w = (const float*)d_in[13];
    const float* ln_mlp_b = (const float*)d_in[14];
    const float* W1 = (const float*)d_in[15];
    const float* b1 = (const float*)d_in[16];
    const float* W2 = (const float*)d_in[17];
    const float* b2 = (const float*)d_in[18];
    float* outp = (float*)d_out;

    char* w = (char*)d_ws;
    ushort_t* xmmN = (ushort_t*)w;    w += 512 * 1024 * 2;
    ushort_t* xvN = (ushort_t*)w;     w += 128 * 1024 * 2;
    ushort_t* xaN = (ushort_t*)w;     w += 256 * 1024 * 2;
    ushort_t* Wqt = (ushort_t*)w;     w += 256 * 1024 * 2;
    ushort_t* Wkvt = (ushort_t*)w;    w += 512 * 2048 * 2;
    ushort_t* Wprojt = (ushort_t*)w;  w += 1024 * 256 * 2;
    ushort_t* W1t = (ushort_t*)w;     w += 4096 * 1024 * 2;
    ushort_t* W2t = (ushort_t*)w;     w += 1024 * 4096 * 2;
    ushort_t* qout = (ushort_t*)w;    w += 512 * 256 * 2;
    ushort_t* kvvb = (ushort_t*)w;    w += 128 * 512 * 2;
    ushort_t* kvab = (ushort_t*)w;    w += 256 * 512 * 2;
    ushort_t* attnout = (ushort_t*)w; w += 512 * 256 * 2;
    float* y = (float*)w;             w += 512 * 1024 * 4;
    ushort_t* h0 = (ushort_t*)w;      w += 512 * 1024 * 2;
    ushort_t* g = (ushort_t*)w;       w += 512 * 4096 * 2;
    float* P = (float*)w;             w += 4 * 512 * 1024 * 4;

    // 1) prep: 3 LayerNorms + Wq/Wkv transposes (64+256 tiles of 64x64)
    LNSeg L0{xmm, ln_mm_w, ln_mm_b, xmmN, 0};
    LNSeg L1{xv, ln_v_w, ln_v_b, xvN, 512};
    LNSeg L2{xa, ln_a_w, ln_a_b, xaN, 640};
    TDesc TQ{Wq, Wqt, 1024, 256, 4, 0};       // 64 tiles
    TDesc TKV{Wkv, Wkvt, 2048, 512, 8, 64};   // 256 tiles
    prep_kernel<<<896 + 320, 256, 0, stream>>>(L0, L1, L2, TQ, TKV);

    // 2) projections (80 blocks) + Wproj transpose (64 blocks)
    GSeg G0{xmmN, Wqt, qout, 1024, 1024, 256, 4, 0};
    GSeg G1{xvN, Wkvt, kvvb, 1024, 2048, 512, 8, 32};
    GSeg G2{xaN, Wkvt + 1024, kvab, 1024, 2048, 512, 8, 48};
    TDesc TP{Wproj, Wprojt, 256, 1024, 16, 0};    // 64 tiles
    projT_kernel<<<80 + 64, 256, 0, stream>>>(G0, G1, G2, TP, 1024);

    // 3) attention (128) + W1 transpose (1024) backfill
    TDesc T1{W1, W1t, 1024, 4096, 64, 0};         // 1024 tiles
    attnT_kernel<<<128 + 1024, 256, 0, stream>>>(qout, kvvb, kvab, attnout,
                                                 T1);

    // 4) y = attnout @ Wproj + bproj + xmm  [512,1024] fp32
    gemm64<3, float><<<dim3(16, 8, 1), 256, 0, stream>>>(
        attnout, 256, Wprojt, 256, y, 1024, bproj, xmm, 256, 0);

    // 5) h0 = LN(y) bf16
    ln_kernel<<<512, 256, 0, stream>>>(y, ln_mlp_w, ln_mlp_b, h0);

    // 6) g = gelu(h0 @ W1 + b1) (512) + W2 transpose (1024) under MFMA cover
    TDesc T2{W2, W2t, 4096, 1024, 16, 0};         // 1024 tiles
    mlp1T_kernel<<<512 + 1024, 256, 0, stream>>>(h0, W1t, b1, g, T2);

    // 7) split-K=4: P[z] = g @ W2 (k-slice z)  [4][512,1024] fp32
    gemm64<4, float><<<dim3(16, 8, 4), 256, 0, stream>>>(
        g, 4096, W2t, 4096, P, 1024, nullptr, nullptr, 1024, 512 * 1024);

    // 8) out = sum P + b2 + y
    reduce_mlp2<<<512, 256, 0, stream>>>(P, y, b2, outp);

    (void)in_sizes; (void)n_in; (void)out_size; (void)ws_size;
}